// Round 1
// baseline (911.941 us; speedup 1.0000x reference)
//
#include <hip/hip_runtime.h>
#include <cstdint>
#include <cstddef>

#define NS 4096
#define TS 16
#define DF 5
#define HD 128
#define EE 32768
#define EDD 32

__device__ __forceinline__ float sigmoidf_(float x){ return 1.f/(1.f+__expf(-x)); }
__device__ __forceinline__ float tanhf_(float x){ return 1.f - 2.f/(1.f+__expf(2.f*x)); }
__device__ __forceinline__ float leaky_(float x){ return x >= 0.f ? x : 0.2f*x; }

// ---------------- sf = x / mean_t(x) ----------------
__global__ void k_sf(const float* __restrict__ x, float* __restrict__ sf){
  int id = blockIdx.x*256 + threadIdx.x; // n*DF + d
  if (id >= NS*DF) return;
  int n = id / DF, d = id % DF;
  const float* xp = x + (size_t)n*TS*DF + d;
  float s = 0.f;
  #pragma unroll
  for (int t=0;t<TS;t++) s += xp[t*DF];
  float inv = (float)TS / s;
  float* sp = sf + (size_t)n*TS*DF + d;
  #pragma unroll
  for (int t=0;t<TS;t++) sp[t*DF] = xp[t*DF]*inv;
}

// ---------------- transpose Whh [512,128] -> [128,512] ----------------
__global__ void k_whhT(const float* __restrict__ Whh, float* __restrict__ WhhT){
  int id = blockIdx.x*256+threadIdx.x;
  if (id >= 512*128) return;
  int g = id >> 7, k = id & 127;
  WhhT[k*512 + g] = Whh[id];
}

// ---------------- LSTM: one block per 16 rows, persistent over T ----------------
__global__ __launch_bounds__(512)
void k_lstm(const float* __restrict__ sf, const float* __restrict__ WhhT,
            const float* __restrict__ Wih, const float* __restrict__ bih,
            const float* __restrict__ bhh, float* __restrict__ cat)
{
  __shared__ float hT[128][20];     // hT[k][r], padded row to 20 floats (16B aligned)
  __shared__ float cbuf[16][128];
  __shared__ float gates[16][512];
  __shared__ float sfb[16*80];      // 16 rows x (16 t x 5 d)
  int tid = threadIdx.x;
  int n0 = blockIdx.x * 16;
  for (int i = tid; i < 128*20; i += 512) ((float*)hT)[i] = 0.f;
  for (int i = tid; i < 16*128; i += 512) ((float*)cbuf)[i] = 0.f;
  for (int i = tid; i < 16*80; i += 512) sfb[i] = sf[(size_t)n0*80 + i];
  int g = tid; // gate column 0..511
  float wd0=Wih[g*5+0],wd1=Wih[g*5+1],wd2=Wih[g*5+2],wd3=Wih[g*5+3],wd4=Wih[g*5+4];
  float bsum = bih[g] + bhh[g];
  __syncthreads();
  for (int t = 0; t < 16; t++){
    float acc[16];
    #pragma unroll
    for (int r=0;r<16;r++){
      const float* s = &sfb[r*80 + t*5];
      acc[r] = bsum + s[0]*wd0 + s[1]*wd1 + s[2]*wd2 + s[3]*wd3 + s[4]*wd4;
    }
    #pragma unroll 4
    for (int k=0;k<128;k++){
      float w = WhhT[k*512 + g];
      float4 h0 = *(const float4*)&hT[k][0];
      float4 h1 = *(const float4*)&hT[k][4];
      float4 h2 = *(const float4*)&hT[k][8];
      float4 h3 = *(const float4*)&hT[k][12];
      acc[0]  = fmaf(h0.x, w, acc[0]);  acc[1]  = fmaf(h0.y, w, acc[1]);
      acc[2]  = fmaf(h0.z, w, acc[2]);  acc[3]  = fmaf(h0.w, w, acc[3]);
      acc[4]  = fmaf(h1.x, w, acc[4]);  acc[5]  = fmaf(h1.y, w, acc[5]);
      acc[6]  = fmaf(h1.z, w, acc[6]);  acc[7]  = fmaf(h1.w, w, acc[7]);
      acc[8]  = fmaf(h2.x, w, acc[8]);  acc[9]  = fmaf(h2.y, w, acc[9]);
      acc[10] = fmaf(h2.z, w, acc[10]); acc[11] = fmaf(h2.w, w, acc[11]);
      acc[12] = fmaf(h3.x, w, acc[12]); acc[13] = fmaf(h3.y, w, acc[13]);
      acc[14] = fmaf(h3.z, w, acc[14]); acc[15] = fmaf(h3.w, w, acc[15]);
    }
    #pragma unroll
    for (int r=0;r<16;r++) gates[r][g] = acc[r];
    __syncthreads();
    #pragma unroll
    for (int q=0;q<4;q++){
      int p = tid + 512*q;
      int r = p >> 7, j = p & 127;
      float iv = sigmoidf_(gates[r][j]);
      float fv = sigmoidf_(gates[r][128+j]);
      float gv = tanhf_(gates[r][256+j]);
      float ov = sigmoidf_(gates[r][384+j]);
      float c = fv*cbuf[r][j] + iv*gv;
      cbuf[r][j] = c;
      float h = ov*tanhf_(c);
      hT[j][r] = h;
      cat[(size_t)((n0+r)*16 + t)*512 + j] = h;  // sr into cat cols 0..127
    }
    __syncthreads();
  }
}

// ---------------- generic fp32 GEMM: C = act(A[M,K] @ B[N,K]^T + bias) ----------------
// BM=128, BN=64, BK=16; block 256; micro-tile 8x4. M%128==0, N%64==0, K%16==0.
__global__ __launch_bounds__(256)
void gemm_bias_act(const float* __restrict__ A, int lda,
                   const float* __restrict__ B, int ldb,
                   const float* __restrict__ bias,
                   float* __restrict__ C, int ldc,
                   int K, int act)
{
  __shared__ float As[16][132];
  __shared__ float Bs[16][68];
  int tid = threadIdx.x;
  size_t m0 = (size_t)blockIdx.x * 128;
  int n0 = blockIdx.y * 64;
  int tm = (tid >> 4) << 3;
  int tn = (tid & 15) << 2;
  float acc[8][4];
  #pragma unroll
  for (int i=0;i<8;i++){
    #pragma unroll
    for (int j=0;j<4;j++) acc[i][j]=0.f;
  }
  for (int k0=0;k0<K;k0+=16){
    int idx = tid;
    #pragma unroll
    for (int rep=0;rep<2;rep++,idx+=256){
      int row = idx >> 2;
      int kq = (idx & 3) << 2;
      float4 a = *(const float4*)&A[(m0+row)*lda + k0 + kq];
      As[kq+0][row]=a.x; As[kq+1][row]=a.y; As[kq+2][row]=a.z; As[kq+3][row]=a.w;
    }
    {
      int row = tid >> 2;
      int kq = (tid & 3) << 2;
      float4 b = *(const float4*)&B[(size_t)(n0+row)*ldb + k0 + kq];
      Bs[kq+0][row]=b.x; Bs[kq+1][row]=b.y; Bs[kq+2][row]=b.z; Bs[kq+3][row]=b.w;
    }
    __syncthreads();
    #pragma unroll
    for (int k=0;k<16;k++){
      float4 a0 = *(const float4*)&As[k][tm];
      float4 a1 = *(const float4*)&As[k][tm+4];
      float4 b  = *(const float4*)&Bs[k][tn];
      float am[8]={a0.x,a0.y,a0.z,a0.w,a1.x,a1.y,a1.z,a1.w};
      float bv[4]={b.x,b.y,b.z,b.w};
      #pragma unroll
      for (int i=0;i<8;i++){
        #pragma unroll
        for (int j=0;j<4;j++)
          acc[i][j] = fmaf(am[i], bv[j], acc[i][j]);
      }
    }
    __syncthreads();
  }
  float bj0=bias[n0+tn+0], bj1=bias[n0+tn+1], bj2=bias[n0+tn+2], bj3=bias[n0+tn+3];
  #pragma unroll
  for (int i=0;i<8;i++){
    float4 o;
    o.x=acc[i][0]+bj0; o.y=acc[i][1]+bj1; o.z=acc[i][2]+bj2; o.w=acc[i][3]+bj3;
    if (act==1){ o.x=leaky_(o.x); o.y=leaky_(o.y); o.z=leaky_(o.z); o.w=leaky_(o.w); }
    *(float4*)&C[(m0+tm+i)*ldc + n0 + tn] = o;
  }
}

// ---------------- CSR build ----------------
__global__ void k_zero_i(int* p, int n){ int i=blockIdx.x*256+threadIdx.x; if(i<n) p[i]=0; }

__global__ void k_count(const int* __restrict__ dst, int* __restrict__ cnt){
  int e = blockIdx.x*256+threadIdx.x;
  atomicAdd(&cnt[dst[e]], 1);
}

__global__ __launch_bounds__(1024)
void k_scan(const int* __restrict__ cnt, int* __restrict__ rs, int* __restrict__ woff){
  __shared__ int buf[1024];
  int tid = threadIdx.x;
  int b = tid*4;
  int v0=cnt[b],v1=cnt[b+1],v2=cnt[b+2],v3=cnt[b+3];
  int s = v0+v1+v2+v3;
  buf[tid]=s;
  __syncthreads();
  for (int off=1; off<1024; off<<=1){
    int t = (tid>=off) ? buf[tid-off] : 0;
    __syncthreads();
    buf[tid] += t;
    __syncthreads();
  }
  int excl = buf[tid] - s;
  rs[b+0]=excl; woff[b+0]=excl; excl+=v0;
  rs[b+1]=excl; woff[b+1]=excl; excl+=v1;
  rs[b+2]=excl; woff[b+2]=excl; excl+=v2;
  rs[b+3]=excl; woff[b+3]=excl;
  if (tid==1023) rs[4096]=excl+v3;
}

__global__ void k_fill(const int* __restrict__ dst, int* __restrict__ woff, int* __restrict__ eidx){
  int e = blockIdx.x*256+threadIdx.x;
  int pos = atomicAdd(&woff[dst[e]], 1);
  eidx[pos]=e;
}

// ---------------- fused message + segment_sum: one block per dst node ----------------
__global__ __launch_bounds__(256)
void k_edge(const float* __restrict__ eqk, const float* __restrict__ ee,
            const int* __restrict__ src, const int* __restrict__ rs,
            const int* __restrict__ eidx, float* __restrict__ ft)
{
  int n = blockIdx.x;
  int tid = threadIdx.x;
  int h = tid & 127, tq = tid >> 7; // fixed h, t in {tq, tq+2, ..., tq+14}
  float acc[8]; float eqv[8];
  #pragma unroll
  for (int q=0;q<8;q++){
    acc[q]=0.f;
    int t = tq + 2*q;
    eqv[q] = eqk[(size_t)((n<<4)+t)*256 + h];
  }
  int i0 = rs[n], i1 = rs[n+1];
  for (int i=i0;i<i1;i++){
    int e = eidx[i];
    int s = src[e];
    float ev = ee[(size_t)e*128 + h];
    const float* ekp = eqk + (size_t)(s<<4)*256 + 128 + h;
    #pragma unroll
    for (int q=0;q<8;q++){
      int t = tq + 2*q;
      float x = eqv[q] + ekp[(size_t)t*256] + ev;
      acc[q] += leaky_(x);
    }
  }
  #pragma unroll
  for (int q=0;q<8;q++){
    int t = tq+2*q;
    ft[(size_t)((n<<4)+t)*128 + h] = acc[q];
  }
}

// ---------------- attention over T + pooling ----------------
__global__ __launch_bounds__(256)
void k_attn(const float* __restrict__ cat, const float* __restrict__ attnW,
            const float* __restrict__ attnB, float* __restrict__ pooled)
{
  __shared__ float ct[16*512];
  __shared__ float sred[4][16];
  int n = blockIdx.x, tid = threadIdx.x;
  for (int i=tid;i<8192;i+=256) ct[i] = cat[(size_t)n*8192 + i];
  __syncthreads();
  int c0 = tid*2, c1 = tid*2+1;
  float w0 = attnW[c0], w1 = attnW[c1];
  float loc[16];
  #pragma unroll
  for (int t=0;t<16;t++) loc[t] = ct[t*512+c0]*w0 + ct[t*512+c1]*w1;
  #pragma unroll
  for (int t=0;t<16;t++){
    float v = loc[t];
    for (int off=1; off<64; off<<=1) v += __shfl_xor(v, off, 64);
    loc[t]=v;
  }
  int wave = tid >> 6, lane = tid & 63;
  if (lane==0){
    #pragma unroll
    for (int t=0;t<16;t++) sred[wave][t]=loc[t];
  }
  __syncthreads();
  float s[16]; float m=-1e30f;
  float ab = attnB[0];
  #pragma unroll
  for (int t=0;t<16;t++){ s[t] = sred[0][t]+sred[1][t]+sred[2][t]+sred[3][t] + ab; m = fmaxf(m, s[t]); }
  float sum=0.f;
  #pragma unroll
  for (int t=0;t<16;t++){ s[t] = __expf(s[t]-m); sum += s[t]; }
  float inv = 1.f/sum;
  float p0=0.f,p1=0.f;
  #pragma unroll
  for (int t=0;t<16;t++){ float a=s[t]*inv; p0 = fmaf(ct[t*512+c0], a, p0); p1 = fmaf(ct[t*512+c1], a, p1); }
  pooled[(size_t)n*512+c0]=p0; pooled[(size_t)n*512+c1]=p1;
}

// ---------------- final: out = leaky(hmlp @ W2 + b2) / sf[:,15,0] - 1 ----------------
__global__ __launch_bounds__(256)
void k_final(const float* __restrict__ hmlp, const float* __restrict__ W2,
             const float* __restrict__ b2, const float* __restrict__ sf,
             float* __restrict__ out)
{
  int tid = threadIdx.x;
  int n = blockIdx.x*4 + (tid>>6);
  int lane = tid & 63;
  const float* hp = hmlp + (size_t)n*128;
  float v = hp[lane]*W2[lane] + hp[64+lane]*W2[64+lane];
  for (int off=1; off<64; off<<=1) v += __shfl_xor(v, off, 64);
  if (lane==0){
    float o = v + b2[0];
    o = leaky_(o);
    out[n] = o / sf[(size_t)n*80 + 75] - 1.f;
  }
}

extern "C" void kernel_launch(void* const* d_in, const int* in_sizes, int n_in,
                              void* d_out, int out_size, void* d_ws, size_t ws_size,
                              hipStream_t stream)
{
  const float* x    = (const float*)d_in[0];
  const float* Wih  = (const float*)d_in[34];
  const float* Whh  = (const float*)d_in[35];
  const float* bih  = (const float*)d_in[36];
  const float* bhh  = (const float*)d_in[37];
  const float* attnW= (const float*)d_in[38];
  const float* attnB= (const float*)d_in[39];
  const float* W1   = (const float*)d_in[40];
  const float* b1   = (const float*)d_in[41];
  const float* W2   = (const float*)d_in[42];
  const float* b2   = (const float*)d_in[43];

  float* ws = (float*)d_ws;
  size_t o = 0;
  float* sf     = ws + o; o += (size_t)NS*TS*DF;        // 327,680
  float* cat    = ws + o; o += (size_t)NS*TS*512;       // 33,554,432
  float* eqk    = ws + o; o += (size_t)NS*TS*256;       // 16,777,216
  float* eebuf  = ws + o; o += (size_t)EE*HD;           // 4,194,304
  float* ft     = ws + o; o += (size_t)NS*TS*HD;        // 8,388,608
  float* pooled = ws + o; o += (size_t)NS*512;          // 2,097,152
  float* hmlp   = ws + o; o += (size_t)NS*HD;           // 524,288
  float* whhT   = ws + o; o += (size_t)128*512;         // 65,536
  int* ip   = (int*)(ws + o);
  int* cnt  = ip;
  int* rs   = ip + 4096;
  int* woff = rs + 4097;
  int* eidx = woff + 4096;

  k_sf  <<<80, 256, 0, stream>>>(x, sf);
  k_whhT<<<256, 256, 0, stream>>>(Whh, whhT);
  k_lstm<<<256, 512, 0, stream>>>(sf, whhT, Wih, bih, bhh, cat);

  for (int g = 0; g < 3; g++){
    int base = 1 + g*11;
    const int*   srcp = (const int*)d_in[base+0];
    const int*   dstp = (const int*)d_in[base+1];
    const float* ef   = (const float*)d_in[base+2];
    const float* Wq   = (const float*)d_in[base+3];
    const float* bq   = (const float*)d_in[base+4];
    const float* Wk   = (const float*)d_in[base+5];
    const float* bk   = (const float*)d_in[base+6];
    const float* We   = (const float*)d_in[base+7];
    const float* be   = (const float*)d_in[base+8];
    const float* Wr   = (const float*)d_in[base+9];
    const float* br   = (const float*)d_in[base+10];

    k_zero_i<<<16, 256, 0, stream>>>(cnt, 4096);
    k_count <<<EE/256, 256, 0, stream>>>(dstp, cnt);
    k_scan  <<<1, 1024, 0, stream>>>(cnt, rs, woff);
    k_fill  <<<EE/256, 256, 0, stream>>>(dstp, woff, eidx);

    dim3 g1(512, 2);  // M=65536, N=128
    gemm_bias_act<<<g1, 256, 0, stream>>>(cat, 512, Wq, 128, bq, eqk,      256, 128, 0);
    gemm_bias_act<<<g1, 256, 0, stream>>>(cat, 512, Wk, 128, bk, eqk+128,  256, 128, 0);
    dim3 g2(EE/128, 2); // M=32768, N=128, K=32
    gemm_bias_act<<<g2, 256, 0, stream>>>(ef, 32, We, 32, be, eebuf, 128, 32, 0);

    k_edge<<<NS, 256, 0, stream>>>(eqk, eebuf, srcp, rs, eidx, ft);

    gemm_bias_act<<<g1, 256, 0, stream>>>(ft, 128, Wr, 128, br, cat + (size_t)(1+g)*128, 512, 128, 0);
  }

  k_attn<<<NS, 256, 0, stream>>>(cat, attnW, attnB, pooled);
  dim3 g3(NS/128, 2); // M=4096, N=128, K=512
  gemm_bias_act<<<g3, 256, 0, stream>>>(pooled, 512, W1, 512, b1, hmlp, 128, 512, 1);
  k_final<<<NS/4, 256, 0, stream>>>(hmlp, W2, b2, sf, (float*)d_out);
}

// Round 2
// 627.304 us; speedup vs baseline: 1.4537x; 1.4537x over previous
//
#include <hip/hip_runtime.h>
#include <cstdint>
#include <cstddef>

#define NS 4096
#define TS 16
#define DF 5
#define HD 128
#define EE 32768
#define EDD 32

typedef __attribute__((ext_vector_type(8))) short bf16x8;
typedef __attribute__((ext_vector_type(4))) float f32x4;

__device__ __forceinline__ float sigmoidf_(float x){ return 1.f/(1.f+__expf(-x)); }
__device__ __forceinline__ float tanhf_(float x){ return 1.f - 2.f/(1.f+__expf(2.f*x)); }
__device__ __forceinline__ float leaky_(float x){ return x >= 0.f ? x : 0.2f*x; }

__device__ __forceinline__ unsigned short f2bf(float x){
  unsigned u = __float_as_uint(x);
  u += 0x7FFF + ((u>>16)&1);   // round-to-nearest-even
  return (unsigned short)(u>>16);
}

__device__ __forceinline__ bf16x8 ld_bf8_lds(const unsigned short* p){
  // two 8B LDS reads (pitch not 16B aligned), assemble bf16x8
  uint2 a = *(const uint2*)p;
  uint2 b = *(const uint2*)(p+4);
  union { unsigned u[4]; bf16x8 v; } x;
  x.u[0]=a.x; x.u[1]=a.y; x.u[2]=b.x; x.u[3]=b.y;
  return x.v;
}

// ---------------- sf = x / mean_t(x) ----------------
__global__ void k_sf(const float* __restrict__ x, float* __restrict__ sf){
  int id = blockIdx.x*256 + threadIdx.x; // n*DF + d
  if (id >= NS*DF) return;
  int n = id / DF, d = id % DF;
  const float* xp = x + (size_t)n*TS*DF + d;
  float s = 0.f;
  #pragma unroll
  for (int t=0;t<TS;t++) s += xp[t*DF];
  float inv = (float)TS / s;
  float* sp = sf + (size_t)n*TS*DF + d;
  #pragma unroll
  for (int t=0;t<TS;t++) sp[t*DF] = xp[t*DF]*inv;
}

// ---------------- fp32 -> bf16 convert ----------------
__global__ void k_cvt(const float* __restrict__ a, unsigned short* __restrict__ b, int n){
  int i = blockIdx.x*256 + threadIdx.x;
  if (i < n) b[i] = f2bf(a[i]);
}

// ---------------- LSTM: MFMA recurrence, one block per 16 rows ----------------
// Whh bf16 B-fragments live in registers (constant over T). h kept as bf16 in
// LDS, row pitch 136 (272B: 16B-aligned reads, 2-way-bank free).
__global__ __launch_bounds__(512)
void k_lstm(const float* __restrict__ sf, const unsigned short* __restrict__ WhhB,
            const float* __restrict__ Wih, const float* __restrict__ bih,
            const float* __restrict__ bhh, float* __restrict__ cat)
{
  __shared__ unsigned short hbuf[16*136];
  __shared__ float gates[16*516];
  __shared__ float sfb[16*80];
  int tid = threadIdx.x;
  int n0 = blockIdx.x * 16;
  int wv = tid>>6, lane = tid&63, lm = lane&15, lq = lane>>4;

  // B fragments: lane holds Whh[g = wv*64+nt*16+lm][k = kt*32+lq*8 .. +8)
  bf16x8 bf[4][4];
  #pragma unroll
  for (int nt=0;nt<4;nt++){
    int g = wv*64 + nt*16 + lm;
    #pragma unroll
    for (int kt=0;kt<4;kt++)
      bf[kt][nt] = *(const bf16x8*)&WhhB[g*128 + kt*32 + lq*8];
  }

  // elementwise role: fixed j, rows r = rbase + 4q
  int j = tid & 127;
  int rbase = tid >> 7;
  float wih[4][5]; float bsum[4];
  #pragma unroll
  for (int gi=0; gi<4; gi++){
    int gc = gi*128 + j;
    #pragma unroll
    for (int d=0; d<5; d++) wih[gi][d] = Wih[gc*5+d];
    bsum[gi] = bih[gc] + bhh[gc];
  }
  float cst[4] = {0.f,0.f,0.f,0.f};

  for (int i=tid;i<16*136;i+=512) hbuf[i] = 0;
  for (int i=tid;i<16*80;i+=512) sfb[i] = sf[(size_t)n0*80 + i];
  __syncthreads();

  for (int t=0;t<16;t++){
    // ---- MFMA phase: gates_mm = h @ Whh^T ----
    bf16x8 af[4];
    #pragma unroll
    for (int kt=0;kt<4;kt++)
      af[kt] = *(const bf16x8*)&hbuf[lm*136 + kt*32 + lq*8];
    #pragma unroll
    for (int nt=0;nt<4;nt++){
      f32x4 acc = {0.f,0.f,0.f,0.f};
      #pragma unroll
      for (int kt=0;kt<4;kt++)
        acc = __builtin_amdgcn_mfma_f32_16x16x32_bf16(af[kt], bf[kt][nt], acc, 0,0,0);
      int col = wv*64 + nt*16 + lm;
      #pragma unroll
      for (int i=0;i<4;i++)
        gates[(lq*4+i)*516 + col] = acc[i];
    }
    __syncthreads();
    // ---- elementwise phase ----
    #pragma unroll
    for (int q=0;q<4;q++){
      int r = rbase + 4*q;
      const float* s = &sfb[r*80 + t*5];
      float pre[4];
      #pragma unroll
      for (int gi=0;gi<4;gi++){
        float a = bsum[gi];
        #pragma unroll
        for (int d=0;d<5;d++) a = fmaf(s[d], wih[gi][d], a);
        pre[gi] = a + gates[r*516 + gi*128 + j];
      }
      float iv = sigmoidf_(pre[0]);
      float fv = sigmoidf_(pre[1]);
      float gv = tanhf_(pre[2]);
      float ov = sigmoidf_(pre[3]);
      float c = fv*cst[q] + iv*gv;
      cst[q] = c;
      float h = ov*tanhf_(c);
      hbuf[r*136 + j] = f2bf(h);
      cat[(size_t)((n0+r)*16 + t)*512 + j] = h;
    }
    __syncthreads();
  }
}

// ---------------- MFMA GEMM: C = act(A[M,K] @ B[N,K]^T + bias) ----------------
// fp32 in/out, bf16 via LDS. BM=128, BN=64, BK=32; 256 threads = 4 waves.
// B operand split at Nsplit between (B,bias) and (B2,bias2) for fused Q|K.
__global__ __launch_bounds__(256)
void gemm_mfma(const float* __restrict__ A, int lda,
               const float* __restrict__ B, const float* __restrict__ B2, int ldb,
               const float* __restrict__ bias, const float* __restrict__ bias2,
               int Nsplit, float* __restrict__ C, int ldc, int K, int act)
{
  __shared__ unsigned short Asb[128*40];
  __shared__ unsigned short Bsb[64*40];
  int tid = threadIdx.x;
  size_t m0 = (size_t)blockIdx.x * 128;
  int n0 = blockIdx.y * 64;
  const float* Bp; const float* bp; int nb;
  if (n0 >= Nsplit){ Bp = B2; bp = bias2; nb = n0 - Nsplit; }
  else            { Bp = B;  bp = bias;  nb = n0; }
  int wv = tid>>6, lane = tid&63, lm = lane&15, lq = lane>>4;

  f32x4 acc[2][4];
  #pragma unroll
  for (int mt=0;mt<2;mt++)
    #pragma unroll
    for (int nt=0;nt<4;nt++)
      acc[mt][nt] = (f32x4){0.f,0.f,0.f,0.f};

  for (int k0=0; k0<K; k0+=32){
    #pragma unroll
    for (int rep=0;rep<4;rep++){
      int idx = tid + rep*256;
      int row = idx>>3, c4 = idx&7;
      float4 a = *(const float4*)&A[(m0+row)*lda + k0 + c4*4];
      unsigned u0 = (unsigned)f2bf(a.x) | ((unsigned)f2bf(a.y)<<16);
      unsigned u1 = (unsigned)f2bf(a.z) | ((unsigned)f2bf(a.w)<<16);
      *(uint2*)&Asb[row*40 + c4*4] = make_uint2(u0,u1);
    }
    #pragma unroll
    for (int rep=0;rep<2;rep++){
      int idx = tid + rep*256;
      int row = idx>>3, c4 = idx&7;
      float4 b = *(const float4*)&Bp[(size_t)(nb+row)*ldb + k0 + c4*4];
      unsigned u0 = (unsigned)f2bf(b.x) | ((unsigned)f2bf(b.y)<<16);
      unsigned u1 = (unsigned)f2bf(b.z) | ((unsigned)f2bf(b.w)<<16);
      *(uint2*)&Bsb[row*40 + c4*4] = make_uint2(u0,u1);
    }
    __syncthreads();
    bf16x8 afr[2], bfr[4];
    #pragma unroll
    for (int mt=0;mt<2;mt++)
      afr[mt] = ld_bf8_lds(&Asb[(wv*32 + mt*16 + lm)*40 + lq*8]);
    #pragma unroll
    for (int nt=0;nt<4;nt++)
      bfr[nt] = ld_bf8_lds(&Bsb[(nt*16 + lm)*40 + lq*8]);
    #pragma unroll
    for (int mt=0;mt<2;mt++)
      #pragma unroll
      for (int nt=0;nt<4;nt++)
        acc[mt][nt] = __builtin_amdgcn_mfma_f32_16x16x32_bf16(afr[mt], bfr[nt], acc[mt][nt], 0,0,0);
    __syncthreads();
  }

  #pragma unroll
  for (int mt=0;mt<2;mt++){
    #pragma unroll
    for (int nt=0;nt<4;nt++){
      float bv = bp[nb + nt*16 + lm];
      int colg = n0 + nt*16 + lm;
      #pragma unroll
      for (int i=0;i<4;i++){
        float o = acc[mt][nt][i] + bv;
        if (act) o = leaky_(o);
        C[(m0 + wv*32 + mt*16 + lq*4 + i)*ldc + colg] = o;
      }
    }
  }
}

// ---------------- CSR build ----------------
__global__ void k_zero_i(int* p, int n){ int i=blockIdx.x*256+threadIdx.x; if(i<n) p[i]=0; }

__global__ void k_count(const int* __restrict__ dst, int* __restrict__ cnt){
  int e = blockIdx.x*256+threadIdx.x;
  atomicAdd(&cnt[dst[e]], 1);
}

__global__ __launch_bounds__(1024)
void k_scan(const int* __restrict__ cnt, int* __restrict__ rs, int* __restrict__ woff){
  __shared__ int buf[1024];
  int tid = threadIdx.x;
  int b = tid*4;
  int v0=cnt[b],v1=cnt[b+1],v2=cnt[b+2],v3=cnt[b+3];
  int s = v0+v1+v2+v3;
  buf[tid]=s;
  __syncthreads();
  for (int off=1; off<1024; off<<=1){
    int t = (tid>=off) ? buf[tid-off] : 0;
    __syncthreads();
    buf[tid] += t;
    __syncthreads();
  }
  int excl = buf[tid] - s;
  rs[b+0]=excl; woff[b+0]=excl; excl+=v0;
  rs[b+1]=excl; woff[b+1]=excl; excl+=v1;
  rs[b+2]=excl; woff[b+2]=excl; excl+=v2;
  rs[b+3]=excl; woff[b+3]=excl;
  if (tid==1023) rs[4096]=excl+v3;
}

__global__ void k_fill(const int* __restrict__ dst, int* __restrict__ woff, int* __restrict__ eidx){
  int e = blockIdx.x*256+threadIdx.x;
  int pos = atomicAdd(&woff[dst[e]], 1);
  eidx[pos]=e;
}

// ---------------- fused message + segment_sum ----------------
__global__ __launch_bounds__(256)
void k_edge(const float* __restrict__ eqk, const float* __restrict__ ee,
            const int* __restrict__ src, const int* __restrict__ rs,
            const int* __restrict__ eidx, float* __restrict__ ft)
{
  int n = blockIdx.x;
  int tid = threadIdx.x;
  int h = tid & 127, tq = tid >> 7;
  float acc[8]; float eqv[8];
  #pragma unroll
  for (int q=0;q<8;q++){
    acc[q]=0.f;
    int t = tq + 2*q;
    eqv[q] = eqk[(size_t)((n<<4)+t)*256 + h];
  }
  int i0 = rs[n], i1 = rs[n+1];
  for (int i=i0;i<i1;i++){
    int e = eidx[i];
    int s = src[e];
    float ev = ee[(size_t)e*128 + h];
    const float* ekp = eqk + (size_t)(s<<4)*256 + 128 + h;
    #pragma unroll
    for (int q=0;q<8;q++){
      int t = tq + 2*q;
      float x = eqv[q] + ekp[(size_t)t*256] + ev;
      acc[q] += leaky_(x);
    }
  }
  #pragma unroll
  for (int q=0;q<8;q++){
    int t = tq+2*q;
    ft[(size_t)((n<<4)+t)*128 + h] = acc[q];
  }
}

// ---------------- attention over T + pooling ----------------
__global__ __launch_bounds__(256)
void k_attn(const float* __restrict__ cat, const float* __restrict__ attnW,
            const float* __restrict__ attnB, float* __restrict__ pooled)
{
  __shared__ float ct[16*512];
  __shared__ float sred[4][16];
  int n = blockIdx.x, tid = threadIdx.x;
  for (int i=tid;i<8192;i+=256) ct[i] = cat[(size_t)n*8192 + i];
  __syncthreads();
  int c0 = tid*2, c1 = tid*2+1;
  float w0 = attnW[c0], w1 = attnW[c1];
  float loc[16];
  #pragma unroll
  for (int t=0;t<16;t++) loc[t] = ct[t*512+c0]*w0 + ct[t*512+c1]*w1;
  #pragma unroll
  for (int t=0;t<16;t++){
    float v = loc[t];
    for (int off=1; off<64; off<<=1) v += __shfl_xor(v, off, 64);
    loc[t]=v;
  }
  int wave = tid >> 6, lane = tid & 63;
  if (lane==0){
    #pragma unroll
    for (int t=0;t<16;t++) sred[wave][t]=loc[t];
  }
  __syncthreads();
  float s[16]; float m=-1e30f;
  float ab = attnB[0];
  #pragma unroll
  for (int t=0;t<16;t++){ s[t] = sred[0][t]+sred[1][t]+sred[2][t]+sred[3][t] + ab; m = fmaxf(m, s[t]); }
  float sum=0.f;
  #pragma unroll
  for (int t=0;t<16;t++){ s[t] = __expf(s[t]-m); sum += s[t]; }
  float inv = 1.f/sum;
  float p0=0.f,p1=0.f;
  #pragma unroll
  for (int t=0;t<16;t++){ float a=s[t]*inv; p0 = fmaf(ct[t*512+c0], a, p0); p1 = fmaf(ct[t*512+c1], a, p1); }
  pooled[(size_t)n*512+c0]=p0; pooled[(size_t)n*512+c1]=p1;
}

// ---------------- final ----------------
__global__ __launch_bounds__(256)
void k_final(const float* __restrict__ hmlp, const float* __restrict__ W2,
             const float* __restrict__ b2, const float* __restrict__ sf,
             float* __restrict__ out)
{
  int tid = threadIdx.x;
  int n = blockIdx.x*4 + (tid>>6);
  int lane = tid & 63;
  const float* hp = hmlp + (size_t)n*128;
  float v = hp[lane]*W2[lane] + hp[64+lane]*W2[64+lane];
  for (int off=1; off<64; off<<=1) v += __shfl_xor(v, off, 64);
  if (lane==0){
    float o = v + b2[0];
    o = leaky_(o);
    out[n] = o / sf[(size_t)n*80 + 75] - 1.f;
  }
}

extern "C" void kernel_launch(void* const* d_in, const int* in_sizes, int n_in,
                              void* d_out, int out_size, void* d_ws, size_t ws_size,
                              hipStream_t stream)
{
  const float* x    = (const float*)d_in[0];
  const float* Wih  = (const float*)d_in[34];
  const float* Whh  = (const float*)d_in[35];
  const float* bih  = (const float*)d_in[36];
  const float* bhh  = (const float*)d_in[37];
  const float* attnW= (const float*)d_in[38];
  const float* attnB= (const float*)d_in[39];
  const float* W1   = (const float*)d_in[40];
  const float* b1   = (const float*)d_in[41];
  const float* W2   = (const float*)d_in[42];
  const float* b2   = (const float*)d_in[43];

  float* ws = (float*)d_ws;
  size_t o = 0;
  float* sf     = ws + o; o += (size_t)NS*TS*DF;
  float* cat    = ws + o; o += (size_t)NS*TS*512;
  float* eqk    = ws + o; o += (size_t)NS*TS*256;
  float* eebuf  = ws + o; o += (size_t)EE*HD;
  float* ft     = ws + o; o += (size_t)NS*TS*HD;
  float* pooled = ws + o; o += (size_t)NS*512;
  float* hmlp   = ws + o; o += (size_t)NS*HD;
  unsigned short* whhB = (unsigned short*)(ws + o); o += (size_t)512*128/2;
  int* ip   = (int*)(ws + o);
  int* cnt  = ip;
  int* rs   = ip + 4096;
  int* woff = rs + 4097;
  int* eidx = woff + 4096;

  k_sf <<<80, 256, 0, stream>>>(x, sf);
  k_cvt<<<256, 256, 0, stream>>>(Whh, whhB, 512*128);
  k_lstm<<<256, 512, 0, stream>>>(sf, whhB, Wih, bih, bhh, cat);

  for (int g = 0; g < 3; g++){
    int base = 1 + g*11;
    const int*   srcp = (const int*)d_in[base+0];
    const int*   dstp = (const int*)d_in[base+1];
    const float* ef   = (const float*)d_in[base+2];
    const float* Wq   = (const float*)d_in[base+3];
    const float* bq   = (const float*)d_in[base+4];
    const float* Wk   = (const float*)d_in[base+5];
    const float* bk   = (const float*)d_in[base+6];
    const float* We   = (const float*)d_in[base+7];
    const float* be   = (const float*)d_in[base+8];
    const float* Wr   = (const float*)d_in[base+9];
    const float* br   = (const float*)d_in[base+10];

    k_zero_i<<<16, 256, 0, stream>>>(cnt, 4096);
    k_count <<<EE/256, 256, 0, stream>>>(dstp, cnt);
    k_scan  <<<1, 1024, 0, stream>>>(cnt, rs, woff);
    k_fill  <<<EE/256, 256, 0, stream>>>(dstp, woff, eidx);

    // fused eq|ek GEMM: [65536,128] @ [Wq;Wk]^T -> eqk [65536,256]
    gemm_mfma<<<dim3(512,4), 256, 0, stream>>>(cat, 512, Wq, Wk, 128, bq, bk, 128,
                                               eqk, 256, 128, 0);
    // e = efeat @ We^T : [32768,32] -> [32768,128]
    gemm_mfma<<<dim3(256,2), 256, 0, stream>>>(ef, 32, We, We, 32, be, be, 1<<30,
                                               eebuf, 128, 32, 0);

    k_edge<<<NS, 256, 0, stream>>>(eqk, eebuf, srcp, rs, eidx, ft);

    // ft @ Wr^T -> cat cols [(1+g)*128 .. )
    gemm_mfma<<<dim3(512,2), 256, 0, stream>>>(ft, 128, Wr, Wr, 128, br, br, 1<<30,
                                               cat + (size_t)(1+g)*128, 512, 128, 0);
  }

  k_attn<<<NS, 256, 0, stream>>>(cat, attnW, attnB, pooled);
  // MLP1: [4096,512] @ W1^T -> [4096,128], leaky
  gemm_mfma<<<dim3(32,2), 256, 0, stream>>>(pooled, 512, W1, W1, 512, b1, b1, 1<<30,
                                            hmlp, 128, 512, 1);
  k_final<<<NS/4, 256, 0, stream>>>(hmlp, W2, b2, sf, (float*)d_out);
}

// Round 3
// 471.361 us; speedup vs baseline: 1.9347x; 1.3308x over previous
//
#include <hip/hip_runtime.h>
#include <cstdint>
#include <cstddef>

#define NS 4096
#define TS 16
#define DF 5
#define HD 128
#define EE 32768
#define EDD 32

typedef __attribute__((ext_vector_type(8))) short bf16x8;
typedef __attribute__((ext_vector_type(4))) float f32x4;

__device__ __forceinline__ float sigmoidf_(float x){ return 1.f/(1.f+__expf(-x)); }
__device__ __forceinline__ float tanhf_(float x){ return 1.f - 2.f/(1.f+__expf(2.f*x)); }
__device__ __forceinline__ float leaky_(float x){ return x >= 0.f ? x : 0.2f*x; }

__device__ __forceinline__ unsigned short f2bf(float x){
  unsigned u = __float_as_uint(x);
  u += 0x7FFF + ((u>>16)&1);   // round-to-nearest-even
  return (unsigned short)(u>>16);
}
__device__ __forceinline__ unsigned packbf(float a, float b){
  return (unsigned)f2bf(a) | ((unsigned)f2bf(b)<<16);
}
__device__ __forceinline__ void unpack2(unsigned u, float& a, float& b){
  a = __uint_as_float(u<<16);
  b = __uint_as_float(u & 0xFFFF0000u);
}
__device__ __forceinline__ void unpack8(uint4 q, float* f){
  unpack2(q.x, f[0], f[1]); unpack2(q.y, f[2], f[3]);
  unpack2(q.z, f[4], f[5]); unpack2(q.w, f[6], f[7]);
}
__device__ __forceinline__ bf16x8 ld_bf8(const unsigned short* p){
  union { uint4 u; bf16x8 v; } x; x.u = *(const uint4*)p; return x.v;
}

// ---------------- sf = x / mean_t(x) ----------------
__global__ void k_sf(const float* __restrict__ x, float* __restrict__ sf){
  int id = blockIdx.x*256 + threadIdx.x;
  if (id >= NS*DF) return;
  int n = id / DF, d = id % DF;
  const float* xp = x + (size_t)n*TS*DF + d;
  float s = 0.f;
  #pragma unroll
  for (int t=0;t<TS;t++) s += xp[t*DF];
  float inv = (float)TS / s;
  float* sp = sf + (size_t)n*TS*DF + d;
  #pragma unroll
  for (int t=0;t<TS;t++) sp[t*DF] = xp[t*DF]*inv;
}

// ---------------- fp32 -> bf16 convert ----------------
__global__ void k_cvt(const float* __restrict__ a, unsigned short* __restrict__ b, int n){
  int i = blockIdx.x*256 + threadIdx.x;
  if (i < n) b[i] = f2bf(a[i]);
}

// ---------------- LSTM: MFMA recurrence, one block per 16 rows ----------------
__global__ __launch_bounds__(512)
void k_lstm(const float* __restrict__ sf, const unsigned short* __restrict__ WhhB,
            const float* __restrict__ Wih, const float* __restrict__ bih,
            const float* __restrict__ bhh, unsigned short* __restrict__ cat)
{
  __shared__ unsigned short hbuf[16*136];
  __shared__ float gates[16*516];
  __shared__ float sfb[16*80];
  int tid = threadIdx.x;
  int n0 = blockIdx.x * 16;
  int wv = tid>>6, lane = tid&63, lm = lane&15, lq = lane>>4;

  bf16x8 bf[4][4];
  #pragma unroll
  for (int nt=0;nt<4;nt++){
    int g = wv*64 + nt*16 + lm;
    #pragma unroll
    for (int kt=0;kt<4;kt++)
      bf[kt][nt] = *(const bf16x8*)&WhhB[g*128 + kt*32 + lq*8];
  }

  int j = tid & 127;
  int rbase = tid >> 7;
  float wih[4][5]; float bsum[4];
  #pragma unroll
  for (int gi=0; gi<4; gi++){
    int gc = gi*128 + j;
    #pragma unroll
    for (int d=0; d<5; d++) wih[gi][d] = Wih[gc*5+d];
    bsum[gi] = bih[gc] + bhh[gc];
  }
  float cst[4] = {0.f,0.f,0.f,0.f};

  for (int i=tid;i<16*136;i+=512) hbuf[i] = 0;
  for (int i=tid;i<16*80;i+=512) sfb[i] = sf[(size_t)n0*80 + i];
  __syncthreads();

  for (int t=0;t<16;t++){
    bf16x8 af[4];
    #pragma unroll
    for (int kt=0;kt<4;kt++)
      af[kt] = *(const bf16x8*)&hbuf[lm*136 + kt*32 + lq*8];
    #pragma unroll
    for (int nt=0;nt<4;nt++){
      f32x4 acc = {0.f,0.f,0.f,0.f};
      #pragma unroll
      for (int kt=0;kt<4;kt++)
        acc = __builtin_amdgcn_mfma_f32_16x16x32_bf16(af[kt], bf[kt][nt], acc, 0,0,0);
      int col = wv*64 + nt*16 + lm;
      #pragma unroll
      for (int i=0;i<4;i++)
        gates[(lq*4+i)*516 + col] = acc[i];
    }
    __syncthreads();
    #pragma unroll
    for (int q=0;q<4;q++){
      int r = rbase + 4*q;
      const float* s = &sfb[r*80 + t*5];
      float pre[4];
      #pragma unroll
      for (int gi=0;gi<4;gi++){
        float a = bsum[gi];
        #pragma unroll
        for (int d=0;d<5;d++) a = fmaf(s[d], wih[gi][d], a);
        pre[gi] = a + gates[r*516 + gi*128 + j];
      }
      float iv = sigmoidf_(pre[0]);
      float fv = sigmoidf_(pre[1]);
      float gv = tanhf_(pre[2]);
      float ov = sigmoidf_(pre[3]);
      float c = fv*cst[q] + iv*gv;
      cst[q] = c;
      float h = ov*tanhf_(c);
      unsigned short hb = f2bf(h);
      hbuf[r*136 + j] = hb;
      cat[(size_t)((n0+r)*16 + t)*512 + j] = hb;
    }
    __syncthreads();
  }
}

// ---------------- MFMA GEMM: C = act(A[M,K] @ B[N,K]^T + bias) ----------------
// ABF: A is bf16 (else fp32, converted in staging). CBF: C stored bf16.
// B fp32 weights. BM=128, BN=64, BK=32. N-split selects (B2,bias2,C2).
template<int ABF, int CBF>
__global__ __launch_bounds__(256)
void gemm_mfma(const void* __restrict__ Av, int lda,
               const float* __restrict__ B, const float* __restrict__ B2, int ldb,
               const float* __restrict__ bias, const float* __restrict__ bias2,
               int Nsplit, void* __restrict__ C1v, void* __restrict__ C2v,
               int ldc, int K, int act)
{
  __shared__ unsigned short Asb[128*40];
  __shared__ unsigned short Bsb[64*40];
  int tid = threadIdx.x;
  size_t m0 = (size_t)blockIdx.x * 128;
  int n0 = blockIdx.y * 64;
  const float* Bp; const float* bp; int nb; void* Cv;
  if (n0 >= Nsplit){ Bp = B2; bp = bias2; nb = n0 - Nsplit; Cv = C2v; }
  else            { Bp = B;  bp = bias;  nb = n0;          Cv = C1v; }
  int wv = tid>>6, lane = tid&63, lm = lane&15, lq = lane>>4;

  f32x4 acc[2][4];
  #pragma unroll
  for (int mt=0;mt<2;mt++)
    #pragma unroll
    for (int nt=0;nt<4;nt++)
      acc[mt][nt] = (f32x4){0.f,0.f,0.f,0.f};

  for (int k0=0; k0<K; k0+=32){
    if (ABF){
      const unsigned short* A = (const unsigned short*)Av;
      #pragma unroll
      for (int rep=0;rep<2;rep++){
        int idx = tid + rep*256;
        int row = idx>>2, c8 = idx&3;
        uint4 a = *(const uint4*)&A[(m0+row)*lda + k0 + c8*8];
        *(uint4*)&Asb[row*40 + c8*8] = a;
      }
    } else {
      const float* A = (const float*)Av;
      #pragma unroll
      for (int rep=0;rep<4;rep++){
        int idx = tid + rep*256;
        int row = idx>>3, c4 = idx&7;
        float4 a = *(const float4*)&A[(m0+row)*lda + k0 + c4*4];
        *(uint2*)&Asb[row*40 + c4*4] = make_uint2(packbf(a.x,a.y), packbf(a.z,a.w));
      }
    }
    #pragma unroll
    for (int rep=0;rep<2;rep++){
      int idx = tid + rep*256;
      int row = idx>>3, c4 = idx&7;
      float4 b = *(const float4*)&Bp[(size_t)(nb+row)*ldb + k0 + c4*4];
      *(uint2*)&Bsb[row*40 + c4*4] = make_uint2(packbf(b.x,b.y), packbf(b.z,b.w));
    }
    __syncthreads();
    bf16x8 afr[2], bfr[4];
    #pragma unroll
    for (int mt=0;mt<2;mt++)
      afr[mt] = ld_bf8(&Asb[(wv*32 + mt*16 + lm)*40 + lq*8]);
    #pragma unroll
    for (int nt=0;nt<4;nt++)
      bfr[nt] = ld_bf8(&Bsb[(nt*16 + lm)*40 + lq*8]);
    #pragma unroll
    for (int mt=0;mt<2;mt++)
      #pragma unroll
      for (int nt=0;nt<4;nt++)
        acc[mt][nt] = __builtin_amdgcn_mfma_f32_16x16x32_bf16(afr[mt], bfr[nt], acc[mt][nt], 0,0,0);
    __syncthreads();
  }

  #pragma unroll
  for (int mt=0;mt<2;mt++){
    #pragma unroll
    for (int nt=0;nt<4;nt++){
      float bv = bp[nb + nt*16 + lm];
      int colg = (n0>=Nsplit ? n0-Nsplit : n0) + nt*16 + lm;
      #pragma unroll
      for (int i=0;i<4;i++){
        float o = acc[mt][nt][i] + bv;
        if (act) o = leaky_(o);
        size_t ridx = (m0 + wv*32 + mt*16 + lq*4 + i)*(size_t)ldc + colg;
        if (CBF) ((unsigned short*)Cv)[ridx] = f2bf(o);
        else     ((float*)Cv)[ridx] = o;
      }
    }
  }
}

// ---------------- CSR build ----------------
__global__ void k_zero_i(int* p, int n){ int i=blockIdx.x*256+threadIdx.x; if(i<n) p[i]=0; }

__global__ void k_count(const int* __restrict__ dst, int* __restrict__ cnt){
  int e = blockIdx.x*256+threadIdx.x;
  atomicAdd(&cnt[dst[e]], 1);
}

__global__ __launch_bounds__(1024)
void k_scan(const int* __restrict__ cnt, int* __restrict__ rs, int* __restrict__ woff){
  __shared__ int buf[1024];
  int tid = threadIdx.x;
  int b = tid*4;
  int v0=cnt[b],v1=cnt[b+1],v2=cnt[b+2],v3=cnt[b+3];
  int s = v0+v1+v2+v3;
  buf[tid]=s;
  __syncthreads();
  for (int off=1; off<1024; off<<=1){
    int t = (tid>=off) ? buf[tid-off] : 0;
    __syncthreads();
    buf[tid] += t;
    __syncthreads();
  }
  int excl = buf[tid] - s;
  rs[b+0]=excl; woff[b+0]=excl; excl+=v0;
  rs[b+1]=excl; woff[b+1]=excl; excl+=v1;
  rs[b+2]=excl; woff[b+2]=excl; excl+=v2;
  rs[b+3]=excl; woff[b+3]=excl;
  if (tid==1023) rs[4096]=excl+v3;
}

__global__ void k_fill(const int* __restrict__ dst, int* __restrict__ woff, int* __restrict__ eidx){
  int e = blockIdx.x*256+threadIdx.x;
  int pos = atomicAdd(&woff[dst[e]], 1);
  eidx[pos]=e;
}

// ---------------- fused message + segment_sum (bf16 in/out) ----------------
// thread: t = tid>>4, h-octet = (tid&15)*8. One uint4 per operand per edge.
__global__ __launch_bounds__(256)
void k_edge(const unsigned short* __restrict__ eqb, const unsigned short* __restrict__ ekb,
            const unsigned short* __restrict__ eeb, const int* __restrict__ src,
            const int* __restrict__ rs, const int* __restrict__ eidx,
            unsigned short* __restrict__ ft)
{
  int n = blockIdx.x;
  int tid = threadIdx.x;
  int t = tid>>4, hb = (tid&15)*8;
  size_t own = ((size_t)(n*16+t))*128 + hb;
  float eqv[8], acc[8];
  unpack8(*(const uint4*)&eqb[own], eqv);
  #pragma unroll
  for (int j=0;j<8;j++) acc[j]=0.f;
  int i0 = rs[n], i1 = rs[n+1];
  for (int i=i0;i<i1;i++){
    int e = eidx[i];
    int s = src[e];
    uint4 kq = *(const uint4*)&ekb[((size_t)(s*16+t))*128 + hb];
    uint4 eq4 = *(const uint4*)&eeb[(size_t)e*128 + hb];
    float kf[8], ef[8];
    unpack8(kq, kf); unpack8(eq4, ef);
    #pragma unroll
    for (int j=0;j<8;j++)
      acc[j] += leaky_(eqv[j] + kf[j] + ef[j]);
  }
  uint4 o;
  o.x = packbf(acc[0],acc[1]); o.y = packbf(acc[2],acc[3]);
  o.z = packbf(acc[4],acc[5]); o.w = packbf(acc[6],acc[7]);
  *(uint4*)&ft[own] = o;
}

// ---------------- attention over T + pooling (bf16 cat/pooled) ----------------
__global__ __launch_bounds__(256)
void k_attn(const unsigned short* __restrict__ cat, const float* __restrict__ attnW,
            const float* __restrict__ attnB, unsigned short* __restrict__ pooled)
{
  __shared__ unsigned short ct[16*512];
  __shared__ float sred[4][16];
  int n = blockIdx.x, tid = threadIdx.x;
  {
    const uint4* srcp = (const uint4*)(cat + (size_t)n*8192);
    uint4* dstp = (uint4*)ct;
    for (int i=tid;i<1024;i+=256) dstp[i] = srcp[i];
  }
  __syncthreads();
  int c0 = tid*2;
  float w0 = attnW[c0], w1 = attnW[c0+1];
  const unsigned* ctu = (const unsigned*)ct;
  float loc[16];
  #pragma unroll
  for (int t=0;t<16;t++){
    float a,b; unpack2(ctu[t*256 + tid], a, b);
    loc[t] = a*w0 + b*w1;
  }
  #pragma unroll
  for (int t=0;t<16;t++){
    float v = loc[t];
    for (int off=1; off<64; off<<=1) v += __shfl_xor(v, off, 64);
    loc[t]=v;
  }
  int wave = tid >> 6, lane = tid & 63;
  if (lane==0){
    #pragma unroll
    for (int t=0;t<16;t++) sred[wave][t]=loc[t];
  }
  __syncthreads();
  float s[16]; float m=-1e30f;
  float ab = attnB[0];
  #pragma unroll
  for (int t=0;t<16;t++){ s[t] = sred[0][t]+sred[1][t]+sred[2][t]+sred[3][t] + ab; m = fmaxf(m, s[t]); }
  float sum=0.f;
  #pragma unroll
  for (int t=0;t<16;t++){ s[t] = __expf(s[t]-m); sum += s[t]; }
  float inv = 1.f/sum;
  float p0=0.f,p1=0.f;
  #pragma unroll
  for (int t=0;t<16;t++){
    float a = s[t]*inv;
    float x,y; unpack2(ctu[t*256 + tid], x, y);
    p0 = fmaf(x, a, p0); p1 = fmaf(y, a, p1);
  }
  ((unsigned*)pooled)[(size_t)n*256 + tid] = packbf(p0,p1);
}

// ---------------- final ----------------
__global__ __launch_bounds__(256)
void k_final(const float* __restrict__ hmlp, const float* __restrict__ W2,
             const float* __restrict__ b2, const float* __restrict__ sf,
             float* __restrict__ out)
{
  int tid = threadIdx.x;
  int n = blockIdx.x*4 + (tid>>6);
  int lane = tid & 63;
  const float* hp = hmlp + (size_t)n*128;
  float v = hp[lane]*W2[lane] + hp[64+lane]*W2[64+lane];
  for (int off=1; off<64; off<<=1) v += __shfl_xor(v, off, 64);
  if (lane==0){
    float o = v + b2[0];
    o = leaky_(o);
    out[n] = o / sf[(size_t)n*80 + 75] - 1.f;
  }
}

extern "C" void kernel_launch(void* const* d_in, const int* in_sizes, int n_in,
                              void* d_out, int out_size, void* d_ws, size_t ws_size,
                              hipStream_t stream)
{
  const float* x    = (const float*)d_in[0];
  const float* Wih  = (const float*)d_in[34];
  const float* Whh  = (const float*)d_in[35];
  const float* bih  = (const float*)d_in[36];
  const float* bhh  = (const float*)d_in[37];
  const float* attnW= (const float*)d_in[38];
  const float* attnB= (const float*)d_in[39];
  const float* W1   = (const float*)d_in[40];
  const float* b1   = (const float*)d_in[41];
  const float* W2   = (const float*)d_in[42];
  const float* b2   = (const float*)d_in[43];

  char* w = (char*)d_ws;
  size_t o = 0;
  unsigned short* cat    = (unsigned short*)(w+o); o += (size_t)NS*TS*512*2;   // 64 MB
  unsigned short* eqb    = (unsigned short*)(w+o); o += (size_t)NS*TS*128*2;   // 16 MB
  unsigned short* ekb    = (unsigned short*)(w+o); o += (size_t)NS*TS*128*2;   // 16 MB
  unsigned short* eeb    = (unsigned short*)(w+o); o += (size_t)EE*128*2;      // 8 MB
  unsigned short* ft     = (unsigned short*)(w+o); o += (size_t)NS*TS*128*2;   // 16 MB
  unsigned short* pooled = (unsigned short*)(w+o); o += (size_t)NS*512*2;      // 4 MB
  float* sf   = (float*)(w+o); o += (size_t)NS*TS*DF*4;
  float* hmlp = (float*)(w+o); o += (size_t)NS*HD*4;
  unsigned short* whhB = (unsigned short*)(w+o); o += (size_t)512*128*2;
  int* ip   = (int*)(w+o);
  int* cnt  = ip;
  int* rs   = ip + 4096;
  int* woff = rs + 4097;
  int* eidx = woff + 4096;

  k_sf <<<80, 256, 0, stream>>>(x, sf);
  k_cvt<<<256, 256, 0, stream>>>(Whh, whhB, 512*128);
  k_lstm<<<256, 512, 0, stream>>>(sf, whhB, Wih, bih, bhh, cat);

  for (int g = 0; g < 3; g++){
    int base = 1 + g*11;
    const int*   srcp = (const int*)d_in[base+0];
    const int*   dstp = (const int*)d_in[base+1];
    const float* ef   = (const float*)d_in[base+2];
    const float* Wq   = (const float*)d_in[base+3];
    const float* bq   = (const float*)d_in[base+4];
    const float* Wk   = (const float*)d_in[base+5];
    const float* bk   = (const float*)d_in[base+6];
    const float* We   = (const float*)d_in[base+7];
    const float* be   = (const float*)d_in[base+8];
    const float* Wr   = (const float*)d_in[base+9];
    const float* br   = (const float*)d_in[base+10];

    k_zero_i<<<16, 256, 0, stream>>>(cnt, 4096);
    k_count <<<EE/256, 256, 0, stream>>>(dstp, cnt);
    k_scan  <<<1, 1024, 0, stream>>>(cnt, rs, woff);
    k_fill  <<<EE/256, 256, 0, stream>>>(dstp, woff, eidx);

    // fused eq|ek GEMM: A=cat(bf16) cols 0..127, split N -> eqb | ekb (bf16)
    gemm_mfma<1,1><<<dim3(512,4), 256, 0, stream>>>(cat, 512, Wq, Wk, 128, bq, bk, 128,
                                                    eqb, ekb, 128, 128, 0);
    // e = efeat @ We^T (fp32 in, bf16 out)
    gemm_mfma<0,1><<<dim3(256,2), 256, 0, stream>>>(ef, 32, We, We, 32, be, be, 1<<30,
                                                    eeb, eeb, 128, 32, 0);

    k_edge<<<NS, 256, 0, stream>>>(eqb, ekb, eeb, srcp, rs, eidx, ft);

    // ft(bf16) @ Wr^T -> cat cols [(1+g)*128 ..) (bf16)
    gemm_mfma<1,1><<<dim3(512,2), 256, 0, stream>>>(ft, 128, Wr, Wr, 128, br, br, 1<<30,
                                                    cat + (size_t)(1+g)*128, cat + (size_t)(1+g)*128,
                                                    512, 128, 0);
  }

  k_attn<<<NS, 256, 0, stream>>>(cat, attnW, attnB, pooled);
  // MLP1: pooled(bf16) @ W1^T -> hmlp fp32, leaky
  gemm_mfma<1,0><<<dim3(32,2), 256, 0, stream>>>(pooled, 512, W1, W1, 512, b1, b1, 1<<30,
                                                 hmlp, hmlp, 128, 512, 1);
  k_final<<<NS/4, 256, 0, stream>>>(hmlp, W2, b2, sf, (float*)d_out);
}

// Round 4
// 434.376 us; speedup vs baseline: 2.0994x; 1.0851x over previous
//
#include <hip/hip_runtime.h>
#include <cstdint>
#include <cstddef>

#define NS 4096
#define TS 16
#define DF 5
#define HD 128
#define EE 32768
#define EDD 32

typedef __attribute__((ext_vector_type(8))) short bf16x8;
typedef __attribute__((ext_vector_type(4))) float f32x4;

__device__ __forceinline__ float sigmoidf_(float x){ return 1.f/(1.f+__expf(-x)); }
__device__ __forceinline__ float tanhf_(float x){ return 1.f - 2.f/(1.f+__expf(2.f*x)); }
__device__ __forceinline__ float leaky_(float x){ return x >= 0.f ? x : 0.2f*x; }

__device__ __forceinline__ unsigned short f2bf(float x){
  unsigned u = __float_as_uint(x);
  u += 0x7FFF + ((u>>16)&1);
  return (unsigned short)(u>>16);
}
__device__ __forceinline__ unsigned packbf(float a, float b){
  return (unsigned)f2bf(a) | ((unsigned)f2bf(b)<<16);
}
__device__ __forceinline__ void unpack2(unsigned u, float& a, float& b){
  a = __uint_as_float(u<<16);
  b = __uint_as_float(u & 0xFFFF0000u);
}
__device__ __forceinline__ void unpack8(uint4 q, float* f){
  unpack2(q.x, f[0], f[1]); unpack2(q.y, f[2], f[3]);
  unpack2(q.z, f[4], f[5]); unpack2(q.w, f[6], f[7]);
}
__device__ __forceinline__ bf16x8 ld_bf8(const unsigned short* p){
  union { uint4 u; bf16x8 v; } x; x.u = *(const uint4*)p; return x.v;
}

struct GemmB {
  const void* A[6];
  const float* B[6];
  const float* bias[6];
  void* C[6];
};
struct P3 { const int* p[3]; };

// ---------------- sf = x / mean_t(x) ----------------
__global__ void k_sf(const float* __restrict__ x, float* __restrict__ sf){
  int id = blockIdx.x*256 + threadIdx.x;
  if (id >= NS*DF) return;
  int n = id / DF, d = id % DF;
  const float* xp = x + (size_t)n*TS*DF + d;
  float s = 0.f;
  #pragma unroll
  for (int t=0;t<TS;t++) s += xp[t*DF];
  float inv = (float)TS / s;
  float* sp = sf + (size_t)n*TS*DF + d;
  #pragma unroll
  for (int t=0;t<TS;t++) sp[t*DF] = xp[t*DF]*inv;
}

__global__ void k_cvt(const float* __restrict__ a, unsigned short* __restrict__ b, int n){
  int i = blockIdx.x*256 + threadIdx.x;
  if (i < n) b[i] = f2bf(a[i]);
}

// ---------------- LSTM: 8 rows/block, 512 blocks (2 blocks/CU) ----------------
__global__ __launch_bounds__(256,2)
void k_lstm(const float* __restrict__ sf, const unsigned short* __restrict__ WhhB,
            const float* __restrict__ Wih, const float* __restrict__ bih,
            const float* __restrict__ bhh, unsigned short* __restrict__ cat)
{
  __shared__ unsigned short hbuf[8*136];
  __shared__ float gates[8*516];
  __shared__ float sfb[8*80];
  int tid = threadIdx.x;
  int n0 = blockIdx.x * 8;
  int wv = tid>>6, lane = tid&63, lm = lane&15, lq = lane>>4;

  // B fragments: wave wv owns gate-cols [wv*128, wv*128+128)
  bf16x8 bfr[8][4];
  #pragma unroll
  for (int nt=0;nt<8;nt++){
    int g = wv*128 + nt*16 + lm;
    #pragma unroll
    for (int kt=0;kt<4;kt++)
      bfr[nt][kt] = *(const bf16x8*)&WhhB[g*128 + kt*32 + lq*8];
  }

  int j = tid & 127;
  int rbase = tid >> 7;       // 0..1; rows r = rbase + 2q
  float wih[4][5]; float bsum[4];
  #pragma unroll
  for (int gi=0; gi<4; gi++){
    int gc = gi*128 + j;
    #pragma unroll
    for (int d=0; d<5; d++) wih[gi][d] = Wih[gc*5+d];
    bsum[gi] = bih[gc] + bhh[gc];
  }
  float cst[4] = {0.f,0.f,0.f,0.f};

  for (int i=tid;i<8*136;i+=256) hbuf[i] = 0;
  for (int i=tid;i<8*80;i+=256) sfb[i] = sf[(size_t)n0*80 + i];
  __syncthreads();

  bf16x8 zf = {0,0,0,0,0,0,0,0};
  for (int t=0;t<16;t++){
    bf16x8 af[4];
    #pragma unroll
    for (int kt=0;kt<4;kt++)
      af[kt] = (lm < 8) ? *(const bf16x8*)&hbuf[lm*136 + kt*32 + lq*8] : zf;
    #pragma unroll
    for (int nt=0;nt<8;nt++){
      f32x4 acc = {0.f,0.f,0.f,0.f};
      #pragma unroll
      for (int kt=0;kt<4;kt++)
        acc = __builtin_amdgcn_mfma_f32_16x16x32_bf16(af[kt], bfr[nt][kt], acc, 0,0,0);
      if (lq < 2){
        int col = wv*128 + nt*16 + lm;
        #pragma unroll
        for (int i=0;i<4;i++)
          gates[(lq*4+i)*516 + col] = acc[i];
      }
    }
    __syncthreads();
    #pragma unroll
    for (int q=0;q<4;q++){
      int r = rbase + 2*q;
      const float* s = &sfb[r*80 + t*5];
      float pre[4];
      #pragma unroll
      for (int gi=0;gi<4;gi++){
        float a = bsum[gi];
        #pragma unroll
        for (int d=0;d<5;d++) a = fmaf(s[d], wih[gi][d], a);
        pre[gi] = a + gates[r*516 + gi*128 + j];
      }
      float iv = sigmoidf_(pre[0]);
      float fv = sigmoidf_(pre[1]);
      float gv = tanhf_(pre[2]);
      float ov = sigmoidf_(pre[3]);
      float c = fv*cst[q] + iv*gv;
      cst[q] = c;
      float h = ov*tanhf_(c);
      unsigned short hb = f2bf(h);
      hbuf[r*136 + j] = hb;
      cat[(size_t)((n0+r)*16 + t)*512 + j] = hb;
    }
    __syncthreads();
  }
}

// ---------------- batched MFMA GEMM: C[p] = act(A[p][M,K] @ B[p][128,K]^T + bias[p]) ----------------
// grid (nproj, M/128). BM=128, BN=128, BK=32, 256 threads.
template<int ABF, int CBF>
__global__ __launch_bounds__(256)
void gemm_mfma_b(GemmB gb, int lda, int ldb, int ldc, int K, int act)
{
  __shared__ unsigned short Asb[128*40];
  __shared__ unsigned short Bsb[128*40];
  int proj = blockIdx.x;
  size_t m0 = (size_t)blockIdx.y * 128;
  const float* Bp = gb.B[proj];
  const float* bp = gb.bias[proj];
  int tid = threadIdx.x;
  int wv = tid>>6, lane = tid&63, lm = lane&15, lq = lane>>4;

  f32x4 acc[2][8];
  #pragma unroll
  for (int mt=0;mt<2;mt++)
    #pragma unroll
    for (int nt=0;nt<8;nt++)
      acc[mt][nt] = (f32x4){0.f,0.f,0.f,0.f};

  for (int k0=0; k0<K; k0+=32){
    if (ABF){
      const unsigned short* A = (const unsigned short*)gb.A[proj];
      #pragma unroll
      for (int rep=0;rep<2;rep++){
        int idx = tid + rep*256;
        int row = idx>>2, c8 = idx&3;
        *(uint4*)&Asb[row*40 + c8*8] = *(const uint4*)&A[(m0+row)*(size_t)lda + k0 + c8*8];
      }
    } else {
      const float* A = (const float*)gb.A[proj];
      #pragma unroll
      for (int rep=0;rep<4;rep++){
        int idx = tid + rep*256;
        int row = idx>>3, c4 = idx&7;
        float4 a = *(const float4*)&A[(m0+row)*(size_t)lda + k0 + c4*4];
        *(uint2*)&Asb[row*40 + c4*4] = make_uint2(packbf(a.x,a.y), packbf(a.z,a.w));
      }
    }
    #pragma unroll
    for (int rep=0;rep<4;rep++){
      int idx = tid + rep*256;
      int row = idx>>3, c4 = idx&7;
      float4 b = *(const float4*)&Bp[(size_t)row*ldb + k0 + c4*4];
      *(uint2*)&Bsb[row*40 + c4*4] = make_uint2(packbf(b.x,b.y), packbf(b.z,b.w));
    }
    __syncthreads();
    bf16x8 afr[2], bfr[8];
    #pragma unroll
    for (int mt=0;mt<2;mt++)
      afr[mt] = ld_bf8(&Asb[(wv*32 + mt*16 + lm)*40 + lq*8]);
    #pragma unroll
    for (int nt=0;nt<8;nt++)
      bfr[nt] = ld_bf8(&Bsb[(nt*16 + lm)*40 + lq*8]);
    #pragma unroll
    for (int mt=0;mt<2;mt++)
      #pragma unroll
      for (int nt=0;nt<8;nt++)
        acc[mt][nt] = __builtin_amdgcn_mfma_f32_16x16x32_bf16(afr[mt], bfr[nt], acc[mt][nt], 0,0,0);
    __syncthreads();
  }

  #pragma unroll
  for (int mt=0;mt<2;mt++){
    #pragma unroll
    for (int nt=0;nt<8;nt++){
      int col = nt*16 + lm;
      float bv = bp[col];
      #pragma unroll
      for (int i=0;i<4;i++){
        float o = acc[mt][nt][i] + bv;
        if (act) o = leaky_(o);
        size_t ridx = (m0 + wv*32 + mt*16 + lq*4 + i)*(size_t)ldc + col;
        if (CBF) ((unsigned short*)gb.C[proj])[ridx] = f2bf(o);
        else     ((float*)gb.C[proj])[ridx] = o;
      }
    }
  }
}

// ---------------- CSR build (batched over 3 graphs) ----------------
__global__ void k_zero_i(int* p, int n){ int i=blockIdx.x*256+threadIdx.x; if(i<n) p[i]=0; }

__global__ void k_count(P3 dst, int* __restrict__ cnt){
  int e = blockIdx.x*256+threadIdx.x;
  int g = blockIdx.y;
  atomicAdd(&cnt[g*4096 + dst.p[g][e]], 1);
}

__global__ __launch_bounds__(1024)
void k_scan(const int* __restrict__ cnt_, int* __restrict__ rs_, int* __restrict__ woff_){
  __shared__ int buf[1024];
  int g = blockIdx.x;
  const int* cnt = cnt_ + g*4096;
  int* rs = rs_ + g*4097;
  int* woff = woff_ + g*4096;
  int tid = threadIdx.x;
  int b = tid*4;
  int v0=cnt[b],v1=cnt[b+1],v2=cnt[b+2],v3=cnt[b+3];
  int s = v0+v1+v2+v3;
  buf[tid]=s;
  __syncthreads();
  for (int off=1; off<1024; off<<=1){
    int t = (tid>=off) ? buf[tid-off] : 0;
    __syncthreads();
    buf[tid] += t;
    __syncthreads();
  }
  int excl = buf[tid] - s;
  rs[b+0]=excl; woff[b+0]=excl; excl+=v0;
  rs[b+1]=excl; woff[b+1]=excl; excl+=v1;
  rs[b+2]=excl; woff[b+2]=excl; excl+=v2;
  rs[b+3]=excl; woff[b+3]=excl;
  if (tid==1023) rs[4096]=excl+v3;
}

__global__ void k_fill(P3 dst, int* __restrict__ woff, int* __restrict__ eidx){
  int e = blockIdx.x*256+threadIdx.x;
  int g = blockIdx.y;
  int pos = atomicAdd(&woff[g*4096 + dst.p[g][e]], 1);
  eidx[g*EE + pos] = e;
}

// ---------------- fused message + segment_sum, batched: grid (NS, 3) ----------------
__global__ __launch_bounds__(256)
void k_edge(const unsigned short* __restrict__ eqk, const unsigned short* __restrict__ eeb,
            P3 src, const int* __restrict__ rs_, const int* __restrict__ eidx_,
            unsigned short* __restrict__ ft_)
{
  int n = blockIdx.x;
  int g = blockIdx.y;
  const unsigned short* eqb = eqk + (size_t)(2*g)  *NS*TS*128;
  const unsigned short* ekb = eqk + (size_t)(2*g+1)*NS*TS*128;
  const unsigned short* eeg = eeb + (size_t)g*EE*128;
  unsigned short* ft = ft_ + (size_t)g*NS*TS*128;
  const int* srcp = src.p[g];
  const int* rs = rs_ + g*4097;
  const int* eidx = eidx_ + g*EE;
  int tid = threadIdx.x;
  int t = tid>>4, hb = (tid&15)*8;
  size_t own = ((size_t)(n*16+t))*128 + hb;
  float eqv[8], acc[8];
  unpack8(*(const uint4*)&eqb[own], eqv);
  #pragma unroll
  for (int j=0;j<8;j++) acc[j]=0.f;
  int i0 = rs[n], i1 = rs[n+1];
  for (int i=i0;i<i1;i++){
    int e = eidx[i];
    int s = srcp[e];
    uint4 kq = *(const uint4*)&ekb[((size_t)(s*16+t))*128 + hb];
    uint4 eq4 = *(const uint4*)&eeg[(size_t)e*128 + hb];
    float kf[8], ef[8];
    unpack8(kq, kf); unpack8(eq4, ef);
    #pragma unroll
    for (int j=0;j<8;j++)
      acc[j] += leaky_(eqv[j] + kf[j] + ef[j]);
  }
  uint4 o;
  o.x = packbf(acc[0],acc[1]); o.y = packbf(acc[2],acc[3]);
  o.z = packbf(acc[4],acc[5]); o.w = packbf(acc[6],acc[7]);
  *(uint4*)&ft[own] = o;
}

// ---------------- attention over T + pooling ----------------
__global__ __launch_bounds__(256)
void k_attn(const unsigned short* __restrict__ cat, const float* __restrict__ attnW,
            const float* __restrict__ attnB, unsigned short* __restrict__ pooled)
{
  __shared__ unsigned short ct[16*512];
  __shared__ float sred[4][16];
  int n = blockIdx.x, tid = threadIdx.x;
  {
    const uint4* srcp = (const uint4*)(cat + (size_t)n*8192);
    uint4* dstp = (uint4*)ct;
    for (int i=tid;i<1024;i+=256) dstp[i] = srcp[i];
  }
  __syncthreads();
  int c0 = tid*2;
  float w0 = attnW[c0], w1 = attnW[c0+1];
  const unsigned* ctu = (const unsigned*)ct;
  float loc[16];
  #pragma unroll
  for (int t=0;t<16;t++){
    float a,b; unpack2(ctu[t*256 + tid], a, b);
    loc[t] = a*w0 + b*w1;
  }
  #pragma unroll
  for (int t=0;t<16;t++){
    float v = loc[t];
    for (int off=1; off<64; off<<=1) v += __shfl_xor(v, off, 64);
    loc[t]=v;
  }
  int wave = tid >> 6, lane = tid & 63;
  if (lane==0){
    #pragma unroll
    for (int t=0;t<16;t++) sred[wave][t]=loc[t];
  }
  __syncthreads();
  float s[16]; float m=-1e30f;
  float ab = attnB[0];
  #pragma unroll
  for (int t=0;t<16;t++){ s[t] = sred[0][t]+sred[1][t]+sred[2][t]+sred[3][t] + ab; m = fmaxf(m, s[t]); }
  float sum=0.f;
  #pragma unroll
  for (int t=0;t<16;t++){ s[t] = __expf(s[t]-m); sum += s[t]; }
  float inv = 1.f/sum;
  float p0=0.f,p1=0.f;
  #pragma unroll
  for (int t=0;t<16;t++){
    float a = s[t]*inv;
    float x,y; unpack2(ctu[t*256 + tid], x, y);
    p0 = fmaf(x, a, p0); p1 = fmaf(y, a, p1);
  }
  ((unsigned*)pooled)[(size_t)n*256 + tid] = packbf(p0,p1);
}

// ---------------- final ----------------
__global__ __launch_bounds__(256)
void k_final(const float* __restrict__ hmlp, const float* __restrict__ W2,
             const float* __restrict__ b2, const float* __restrict__ sf,
             float* __restrict__ out)
{
  int tid = threadIdx.x;
  int n = blockIdx.x*4 + (tid>>6);
  int lane = tid & 63;
  const float* hp = hmlp + (size_t)n*128;
  float v = hp[lane]*W2[lane] + hp[64+lane]*W2[64+lane];
  for (int off=1; off<64; off<<=1) v += __shfl_xor(v, off, 64);
  if (lane==0){
    float o = v + b2[0];
    o = leaky_(o);
    out[n] = o / sf[(size_t)n*80 + 75] - 1.f;
  }
}

extern "C" void kernel_launch(void* const* d_in, const int* in_sizes, int n_in,
                              void* d_out, int out_size, void* d_ws, size_t ws_size,
                              hipStream_t stream)
{
  const float* x    = (const float*)d_in[0];
  const float* Wih  = (const float*)d_in[34];
  const float* Whh  = (const float*)d_in[35];
  const float* bih  = (const float*)d_in[36];
  const float* bhh  = (const float*)d_in[37];
  const float* attnW= (const float*)d_in[38];
  const float* attnB= (const float*)d_in[39];
  const float* W1   = (const float*)d_in[40];
  const float* b1   = (const float*)d_in[41];
  const float* W2   = (const float*)d_in[42];
  const float* b2   = (const float*)d_in[43];

  char* w = (char*)d_ws;
  size_t o = 0;
  unsigned short* cat    = (unsigned short*)(w+o); o += (size_t)NS*TS*512*2;      // 64 MiB
  unsigned short* eqk    = (unsigned short*)(w+o); o += (size_t)6*NS*TS*128*2;    // 96 MiB (q0,k0,q1,k1,q2,k2)
  unsigned short* eeb    = (unsigned short*)(w+o); o += (size_t)3*EE*128*2;       // 24 MiB
  unsigned short* ft     = (unsigned short*)(w+o); o += (size_t)3*NS*TS*128*2;    // 48 MiB
  unsigned short* pooled = (unsigned short*)(w+o); o += (size_t)NS*512*2;         // 4 MiB
  float* sf   = (float*)(w+o); o += (size_t)NS*TS*DF*4;
  float* hmlp = (float*)(w+o); o += (size_t)NS*HD*4;
  unsigned short* whhB = (unsigned short*)(w+o); o += (size_t)512*128*2;
  int* cnt  = (int*)(w+o); o += 3*4096*4;
  int* rs   = (int*)(w+o); o += 3*4097*4;
  int* woff = (int*)(w+o); o += 3*4096*4;
  int* eidx = (int*)(w+o); o += (size_t)3*EE*4;

  P3 dsts = {{ (const int*)d_in[2], (const int*)d_in[13], (const int*)d_in[24] }};
  P3 srcs = {{ (const int*)d_in[1], (const int*)d_in[12], (const int*)d_in[23] }};

  k_sf <<<80, 256, 0, stream>>>(x, sf);
  k_cvt<<<256, 256, 0, stream>>>(Whh, whhB, 512*128);
  k_lstm<<<512, 256, 0, stream>>>(sf, whhB, Wih, bih, bhh, cat);

  // CSR for all 3 graphs
  k_zero_i<<<48, 256, 0, stream>>>(cnt, 3*4096);
  k_count <<<dim3(EE/256,3), 256, 0, stream>>>(dsts, cnt);
  k_scan  <<<3, 1024, 0, stream>>>(cnt, rs, woff);
  k_fill  <<<dim3(EE/256,3), 256, 0, stream>>>(dsts, woff, eidx);

  // QK: 6 projections off the same A (cat cols 0..127), proj fastest for L2 reuse
  {
    GemmB gb;
    for (int g=0; g<3; g++){
      int base = 1 + g*11;
      gb.A[2*g] = cat;   gb.A[2*g+1] = cat;
      gb.B[2*g]    = (const float*)d_in[base+3]; // Wq
      gb.bias[2*g] = (const float*)d_in[base+4]; // bq
      gb.B[2*g+1]    = (const float*)d_in[base+5]; // Wk
      gb.bias[2*g+1] = (const float*)d_in[base+6]; // bk
      gb.C[2*g]   = eqk + (size_t)(2*g)  *NS*TS*128;
      gb.C[2*g+1] = eqk + (size_t)(2*g+1)*NS*TS*128;
    }
    gemm_mfma_b<1,1><<<dim3(6,512), 256, 0, stream>>>(gb, 512, 128, 128, 128, 0);
  }
  // ee: 3 projections, fp32 A
  {
    GemmB gb;
    for (int g=0; g<3; g++){
      int base = 1 + g*11;
      gb.A[g]    = (const float*)d_in[base+2]; // efeat
      gb.B[g]    = (const float*)d_in[base+7]; // We
      gb.bias[g] = (const float*)d_in[base+8]; // be
      gb.C[g]    = eeb + (size_t)g*EE*128;
    }
    gemm_mfma_b<0,1><<<dim3(3,EE/128), 256, 0, stream>>>(gb, 32, 32, 128, 32, 0);
  }

  k_edge<<<dim3(NS,3), 256, 0, stream>>>(eqk, eeb, srcs, rs, eidx, ft);

  // Wr: 3 projections, ft[g] -> cat cols (1+g)*128
  {
    GemmB gb;
    for (int g=0; g<3; g++){
      int base = 1 + g*11;
      gb.A[g]    = ft + (size_t)g*NS*TS*128;
      gb.B[g]    = (const float*)d_in[base+9];  // Wr
      gb.bias[g] = (const float*)d_in[base+10]; // br
      gb.C[g]    = cat + (size_t)(1+g)*128;
    }
    gemm_mfma_b<1,1><<<dim3(3,512), 256, 0, stream>>>(gb, 128, 128, 512, 128, 0);
  }

  k_attn<<<NS, 256, 0, stream>>>(cat, attnW, attnB, pooled);
  // MLP1
  {
    GemmB gb;
    gb.A[0] = pooled; gb.B[0] = W1; gb.bias[0] = b1; gb.C[0] = hmlp;
    gemm_mfma_b<1,0><<<dim3(1,32), 256, 0, stream>>>(gb, 512, 512, 128, 512, 1);
  }
  k_final<<<NS/4, 256, 0, stream>>>(hmlp, W2, b2, sf, (float*)d_out);
}

// Round 5
// 416.026 us; speedup vs baseline: 2.1920x; 1.0441x over previous
//
#include <hip/hip_runtime.h>
#include <cstdint>
#include <cstddef>

#define NS 4096
#define TS 16
#define DF 5
#define HD 128
#define EE 32768
#define EDD 32

typedef __attribute__((ext_vector_type(8))) short bf16x8;
typedef __attribute__((ext_vector_type(4))) float f32x4;

__device__ __forceinline__ float sigmoidf_(float x){ return 1.f/(1.f+__expf(-x)); }
__device__ __forceinline__ float tanhf_(float x){ return 1.f - 2.f/(1.f+__expf(2.f*x)); }
__device__ __forceinline__ float leaky_(float x){ return x >= 0.f ? x : 0.2f*x; }

__device__ __forceinline__ unsigned short f2bf(float x){
  unsigned u = __float_as_uint(x);
  u += 0x7FFF + ((u>>16)&1);
  return (unsigned short)(u>>16);
}
__device__ __forceinline__ unsigned packbf(float a, float b){
  return (unsigned)f2bf(a) | ((unsigned)f2bf(b)<<16);
}
__device__ __forceinline__ void unpack2(unsigned u, float& a, float& b){
  a = __uint_as_float(u<<16);
  b = __uint_as_float(u & 0xFFFF0000u);
}
__device__ __forceinline__ void unpack8(uint4 q, float* f){
  unpack2(q.x, f[0], f[1]); unpack2(q.y, f[2], f[3]);
  unpack2(q.z, f[4], f[5]); unpack2(q.w, f[6], f[7]);
}
__device__ __forceinline__ bf16x8 ld_bf8(const unsigned short* p){
  union { uint4 u; bf16x8 v; } x; x.u = *(const uint4*)p; return x.v;
}

// ================= generic MFMA GEMM device function =================
// C = act(A[M,K] @ B[128,K]^T + bias), tile BM=128 x BN=128, BK=32, 256 thr.
template<int ABF, int CBF>
__device__ __forceinline__ void gemm_dev(const void* Av, int lda,
    const float* __restrict__ Bp, int ldb, const float* __restrict__ bp,
    void* Cv, int ldc, int K, int act, size_t m0,
    unsigned short* Asb, unsigned short* Bsb)
{
  int tid = threadIdx.x;
  int wv = tid>>6, lane = tid&63, lm = lane&15, lq = lane>>4;
  f32x4 acc[2][8];
  #pragma unroll
  for (int mt=0;mt<2;mt++)
    #pragma unroll
    for (int nt=0;nt<8;nt++)
      acc[mt][nt] = (f32x4){0.f,0.f,0.f,0.f};

  for (int k0=0; k0<K; k0+=32){
    if (ABF){
      const unsigned short* A = (const unsigned short*)Av;
      #pragma unroll
      for (int rep=0;rep<2;rep++){
        int idx = tid + rep*256;
        int row = idx>>2, c8 = idx&3;
        *(uint4*)&Asb[row*40 + c8*8] = *(const uint4*)&A[(m0+row)*(size_t)lda + k0 + c8*8];
      }
    } else {
      const float* A = (const float*)Av;
      #pragma unroll
      for (int rep=0;rep<4;rep++){
        int idx = tid + rep*256;
        int row = idx>>3, c4 = idx&7;
        float4 a = *(const float4*)&A[(m0+row)*(size_t)lda + k0 + c4*4];
        *(uint2*)&Asb[row*40 + c4*4] = make_uint2(packbf(a.x,a.y), packbf(a.z,a.w));
      }
    }
    #pragma unroll
    for (int rep=0;rep<4;rep++){
      int idx = tid + rep*256;
      int row = idx>>3, c4 = idx&7;
      float4 b = *(const float4*)&Bp[(size_t)row*ldb + k0 + c4*4];
      *(uint2*)&Bsb[row*40 + c4*4] = make_uint2(packbf(b.x,b.y), packbf(b.z,b.w));
    }
    __syncthreads();
    bf16x8 afr[2], bfr[8];
    #pragma unroll
    for (int mt=0;mt<2;mt++)
      afr[mt] = ld_bf8(&Asb[(wv*32 + mt*16 + lm)*40 + lq*8]);
    #pragma unroll
    for (int nt=0;nt<8;nt++)
      bfr[nt] = ld_bf8(&Bsb[(nt*16 + lm)*40 + lq*8]);
    #pragma unroll
    for (int mt=0;mt<2;mt++)
      #pragma unroll
      for (int nt=0;nt<8;nt++)
        acc[mt][nt] = __builtin_amdgcn_mfma_f32_16x16x32_bf16(afr[mt], bfr[nt], acc[mt][nt], 0,0,0);
    __syncthreads();
  }

  #pragma unroll
  for (int mt=0;mt<2;mt++){
    #pragma unroll
    for (int nt=0;nt<8;nt++){
      int col = nt*16 + lm;
      float bv = bp[col];
      #pragma unroll
      for (int i=0;i<4;i++){
        float o = acc[mt][nt][i] + bv;
        if (act) o = leaky_(o);
        size_t ridx = (m0 + wv*32 + mt*16 + lq*4 + i)*(size_t)ldc + col;
        if (CBF) ((unsigned short*)Cv)[ridx] = f2bf(o);
        else     ((float*)Cv)[ridx] = o;
      }
    }
  }
}

// ================= LSTM 8 rows/block device function =================
__device__ void lstm8_dev(int blk, const float* __restrict__ sf,
                          const unsigned short* __restrict__ WhhB,
                          const float* __restrict__ Wih, const float* __restrict__ bih,
                          const float* __restrict__ bhh, unsigned short* __restrict__ cat,
                          char* smem)
{
  float* gates = (float*)smem;                          // 8*516*4 = 16512
  unsigned short* hbuf = (unsigned short*)(smem+16512); // 8*136*2 = 2176
  float* sfb = (float*)(smem+16512+2176);               // 8*80*4  = 2560
  int tid = threadIdx.x;
  int n0 = blk*8;
  int wv = tid>>6, lane = tid&63, lm = lane&15, lq = lane>>4;

  // B fragments: wave wv owns gate cols [wv*128, wv*128+128)
  bf16x8 bfr[8][4];
  #pragma unroll
  for (int nt=0;nt<8;nt++){
    int g = wv*128 + nt*16 + lm;
    #pragma unroll
    for (int kt=0;kt<4;kt++)
      bfr[nt][kt] = *(const bf16x8*)&WhhB[g*128 + kt*32 + lq*8];
  }

  int j = tid & 127;
  int rb = tid >> 7;  // rows r = rb + 2q
  float wih[4][5]; float bsum[4];
  #pragma unroll
  for (int gi=0; gi<4; gi++){
    int gc = gi*128 + j;
    #pragma unroll
    for (int d=0; d<5; d++) wih[gi][d] = Wih[gc*5+d];
    bsum[gi] = bih[gc] + bhh[gc];
  }
  float cst[4] = {0.f,0.f,0.f,0.f};

  for (int i=tid;i<544;i+=256) ((unsigned*)hbuf)[i] = 0;
  for (int i=tid;i<640;i+=256) sfb[i] = sf[(size_t)n0*80 + i];
  __syncthreads();

  bf16x8 zf = {0,0,0,0,0,0,0,0};
  for (int t=0;t<16;t++){
    bf16x8 af[4];
    #pragma unroll
    for (int kt=0;kt<4;kt++)
      af[kt] = (lm < 8) ? *(const bf16x8*)&hbuf[lm*136 + kt*32 + lq*8] : zf;
    #pragma unroll
    for (int nt=0;nt<8;nt++){
      f32x4 acc = {0.f,0.f,0.f,0.f};
      #pragma unroll
      for (int kt=0;kt<4;kt++)
        acc = __builtin_amdgcn_mfma_f32_16x16x32_bf16(af[kt], bfr[nt][kt], acc, 0,0,0);
      if (lq < 2){
        int col = wv*128 + nt*16 + lm;
        #pragma unroll
        for (int i=0;i<4;i++)
          gates[(lq*4+i)*516 + col] = acc[i];
      }
    }
    __syncthreads();
    #pragma unroll
    for (int q=0;q<4;q++){
      int r = rb + 2*q;
      const float* s = &sfb[r*80 + t*5];
      float pre[4];
      #pragma unroll
      for (int gi=0;gi<4;gi++){
        float a = bsum[gi];
        #pragma unroll
        for (int d=0;d<5;d++) a = fmaf(s[d], wih[gi][d], a);
        pre[gi] = a + gates[r*516 + gi*128 + j];
      }
      float iv = sigmoidf_(pre[0]);
      float fv = sigmoidf_(pre[1]);
      float gv = tanhf_(pre[2]);
      float ov = sigmoidf_(pre[3]);
      float c = fv*cst[q] + iv*gv;
      cst[q] = c;
      float h = ov*tanhf_(c);
      unsigned short hb16 = f2bf(h);
      hbuf[r*136 + j] = hb16;
      cat[(size_t)((n0+r)*16 + t)*512 + j] = hb16;
    }
    __syncthreads();
  }
}

// ================= prolog: sf | cvt Whh | zero cnt =================
__global__ __launch_bounds__(256)
void k_prolog(const float* __restrict__ x, float* __restrict__ sf,
              const float* __restrict__ Whh, unsigned short* __restrict__ whhB,
              int* __restrict__ cnt)
{
  int b = blockIdx.x, tid = threadIdx.x;
  if (b < 80){
    int id = b*256 + tid;
    if (id < NS*DF){
      int n = id / DF, d = id % DF;
      const float* xp = x + (size_t)n*TS*DF + d;
      float s = 0.f;
      #pragma unroll
      for (int t=0;t<TS;t++) s += xp[t*DF];
      float inv = (float)TS / s;
      float* sp = sf + (size_t)n*TS*DF + d;
      #pragma unroll
      for (int t=0;t<TS;t++) sp[t*DF] = xp[t*DF]*inv;
    }
  } else if (b < 336){
    int i = (b-80)*256 + tid;
    whhB[i] = f2bf(Whh[i]);
  } else {
    int i = (b-336)*256 + tid;
    cnt[i] = 0;
  }
}

// ================= mega1: lstm (512) | ee GEMM (768) | count (384) =================
struct M1 {
  const float *sf, *Wih, *bih, *bhh;
  const unsigned short* WhhB;
  unsigned short* cat;
  const float *ef[3]; const float *We[3]; const float *be[3];
  unsigned short* eeb;
  const int* dst[3];
  int* cnt;
};
__global__ __launch_bounds__(256,2)
void k_mega1(M1 p)
{
  __shared__ __align__(16) char smem[21504];
  int b = blockIdx.x;
  if (b < 512){
    lstm8_dev(b, p.sf, p.WhhB, p.Wih, p.bih, p.bhh, p.cat, smem);
  } else if (b < 1280){
    int idx = b - 512;
    int proj = idx % 3, mt = idx / 3;
    unsigned short* Asb = (unsigned short*)smem;
    unsigned short* Bsb = Asb + 128*40;
    gemm_dev<0,1>(p.ef[proj], 32, p.We[proj], 32, p.be[proj],
                  p.eeb + (size_t)proj*EE*128, 128, 32, 0, (size_t)mt*128, Asb, Bsb);
  } else {
    int idx = b - 1280;
    int g = idx >> 7, blk = idx & 127;
    int e = blk*256 + threadIdx.x;
    atomicAdd(&p.cnt[g*4096 + p.dst[g][e]], 1);
  }
}

// ================= scan =================
__global__ __launch_bounds__(1024)
void k_scan(const int* __restrict__ cnt_, int* __restrict__ rs_, int* __restrict__ woff_){
  __shared__ int buf[1024];
  int g = blockIdx.x;
  const int* cnt = cnt_ + g*4096;
  int* rs = rs_ + g*4097;
  int* woff = woff_ + g*4096;
  int tid = threadIdx.x;
  int b = tid*4;
  int v0=cnt[b],v1=cnt[b+1],v2=cnt[b+2],v3=cnt[b+3];
  int s = v0+v1+v2+v3;
  buf[tid]=s;
  __syncthreads();
  for (int off=1; off<1024; off<<=1){
    int t = (tid>=off) ? buf[tid-off] : 0;
    __syncthreads();
    buf[tid] += t;
    __syncthreads();
  }
  int excl = buf[tid] - s;
  rs[b+0]=excl; woff[b+0]=excl; excl+=v0;
  rs[b+1]=excl; woff[b+1]=excl; excl+=v1;
  rs[b+2]=excl; woff[b+2]=excl; excl+=v2;
  rs[b+3]=excl; woff[b+3]=excl;
  if (tid==1023) rs[4096]=excl+v3;
}

// ================= mega2: QK GEMM (3072) | fill (384) =================
struct M2 {
  const unsigned short* cat;
  const float* W[6]; const float* bias[6];
  unsigned short* eqk;
  const int* dst[3];
  int* woff; int* eidx;
};
__global__ __launch_bounds__(256)
void k_mega2(M2 p)
{
  __shared__ __align__(16) unsigned short Asb[128*40];
  __shared__ __align__(16) unsigned short Bsb[128*40];
  int b = blockIdx.x;
  if (b < 3072){
    int proj = b % 6, mt = b / 6;
    gemm_dev<1,1>(p.cat, 512, p.W[proj], 128, p.bias[proj],
                  p.eqk + (size_t)proj*NS*TS*128, 128, 128, 0, (size_t)mt*128, Asb, Bsb);
  } else {
    int idx = b - 3072;
    int g = idx >> 7, blk = idx & 127;
    int e = blk*256 + threadIdx.x;
    int pos = atomicAdd(&p.woff[g*4096 + p.dst[g][e]], 1);
    p.eidx[g*EE + pos] = e;
  }
}

// ================= k_edge: t-sliced gather, grid (256,16,3) =================
struct P3 { const int* p[3]; };
__global__ __launch_bounds__(256)
void k_edge(const unsigned short* __restrict__ eqk, const unsigned short* __restrict__ eeb,
            P3 src, const int* __restrict__ rs_, const int* __restrict__ eidx_,
            unsigned short* __restrict__ ft_)
{
  int nb = blockIdx.x, t = blockIdx.y, g = blockIdx.z;
  const unsigned short* eqb = eqk + (size_t)(2*g)  *NS*TS*128;
  const unsigned short* ekb = eqk + (size_t)(2*g+1)*NS*TS*128;
  const unsigned short* eeg = eeb + (size_t)g*EE*128;
  unsigned short* ft = ft_ + (size_t)g*NS*TS*128;
  const int* srcp = src.p[g];
  const int* rs = rs_ + g*4097;
  const int* eidx = eidx_ + g*EE;
  int tid = threadIdx.x;
  int n = nb*16 + (tid>>4);
  int hb = (tid&15)*8;
  size_t own = ((size_t)(n*16+t))*128 + hb;
  float eqv[8], acc[8];
  unpack8(*(const uint4*)&eqb[own], eqv);
  #pragma unroll
  for (int j=0;j<8;j++) acc[j]=0.f;
  int i0 = rs[n], i1 = rs[n+1];
  for (int i=i0;i<i1;i++){
    int e = eidx[i];
    int s = srcp[e];
    uint4 kq = *(const uint4*)&ekb[((size_t)(s*16+t))*128 + hb];
    uint4 eq4 = *(const uint4*)&eeg[(size_t)e*128 + hb];
    float kf[8], ef[8];
    unpack8(kq, kf); unpack8(eq4, ef);
    #pragma unroll
    for (int j=0;j<8;j++)
      acc[j] += leaky_(eqv[j] + kf[j] + ef[j]);
  }
  uint4 o;
  o.x = packbf(acc[0],acc[1]); o.y = packbf(acc[2],acc[3]);
  o.z = packbf(acc[4],acc[5]); o.w = packbf(acc[6],acc[7]);
  *(uint4*)&ft[own] = o;
}

// ================= Wr GEMM: grid (3,512) =================
struct WrP {
  const unsigned short* A[3];
  const float* B[3]; const float* bias[3];
  unsigned short* C[3];
};
__global__ __launch_bounds__(256)
void k_wr(WrP p)
{
  __shared__ __align__(16) unsigned short Asb[128*40];
  __shared__ __align__(16) unsigned short Bsb[128*40];
  int proj = blockIdx.x;
  size_t m0 = (size_t)blockIdx.y * 128;
  gemm_dev<1,1>(p.A[proj], 128, p.B[proj], 128, p.bias[proj],
                p.C[proj], 512, 128, 0, m0, Asb, Bsb);
}

// ================= attention + pooling =================
__global__ __launch_bounds__(256)
void k_attn(const unsigned short* __restrict__ cat, const float* __restrict__ attnW,
            const float* __restrict__ attnB, unsigned short* __restrict__ pooled)
{
  __shared__ unsigned short ct[16*512];
  __shared__ float sred[4][16];
  int n = blockIdx.x, tid = threadIdx.x;
  {
    const uint4* srcp = (const uint4*)(cat + (size_t)n*8192);
    uint4* dstp = (uint4*)ct;
    for (int i=tid;i<1024;i+=256) dstp[i] = srcp[i];
  }
  __syncthreads();
  int c0 = tid*2;
  float w0 = attnW[c0], w1 = attnW[c0+1];
  const unsigned* ctu = (const unsigned*)ct;
  float loc[16];
  #pragma unroll
  for (int t=0;t<16;t++){
    float a,b; unpack2(ctu[t*256 + tid], a, b);
    loc[t] = a*w0 + b*w1;
  }
  #pragma unroll
  for (int t=0;t<16;t++){
    float v = loc[t];
    for (int off=1; off<64; off<<=1) v += __shfl_xor(v, off, 64);
    loc[t]=v;
  }
  int wave = tid >> 6, lane = tid & 63;
  if (lane==0){
    #pragma unroll
    for (int t=0;t<16;t++) sred[wave][t]=loc[t];
  }
  __syncthreads();
  float s[16]; float m=-1e30f;
  float ab = attnB[0];
  #pragma unroll
  for (int t=0;t<16;t++){ s[t] = sred[0][t]+sred[1][t]+sred[2][t]+sred[3][t] + ab; m = fmaxf(m, s[t]); }
  float sum=0.f;
  #pragma unroll
  for (int t=0;t<16;t++){ s[t] = __expf(s[t]-m); sum += s[t]; }
  float inv = 1.f/sum;
  float p0=0.f,p1=0.f;
  #pragma unroll
  for (int t=0;t<16;t++){
    float a = s[t]*inv;
    float x,y; unpack2(ctu[t*256 + tid], x, y);
    p0 = fmaf(x, a, p0); p1 = fmaf(y, a, p1);
  }
  ((unsigned*)pooled)[(size_t)n*256 + tid] = packbf(p0,p1);
}

// ================= MLP1 GEMM: grid 32 =================
__global__ __launch_bounds__(256)
void k_mlp(const unsigned short* __restrict__ pooled, const float* __restrict__ W1,
           const float* __restrict__ b1, float* __restrict__ hmlp)
{
  __shared__ __align__(16) unsigned short Asb[128*40];
  __shared__ __align__(16) unsigned short Bsb[128*40];
  gemm_dev<1,0>(pooled, 512, W1, 512, b1, hmlp, 128, 512, 1,
                (size_t)blockIdx.x*128, Asb, Bsb);
}

// ================= final =================
__global__ __launch_bounds__(256)
void k_final(const float* __restrict__ hmlp, const float* __restrict__ W2,
             const float* __restrict__ b2, const float* __restrict__ sf,
             float* __restrict__ out)
{
  int tid = threadIdx.x;
  int n = blockIdx.x*4 + (tid>>6);
  int lane = tid & 63;
  const float* hp = hmlp + (size_t)n*128;
  float v = hp[lane]*W2[lane] + hp[64+lane]*W2[64+lane];
  for (int off=1; off<64; off<<=1) v += __shfl_xor(v, off, 64);
  if (lane==0){
    float o = v + b2[0];
    o = leaky_(o);
    out[n] = o / sf[(size_t)n*80 + 75] - 1.f;
  }
}

extern "C" void kernel_launch(void* const* d_in, const int* in_sizes, int n_in,
                              void* d_out, int out_size, void* d_ws, size_t ws_size,
                              hipStream_t stream)
{
  const float* x    = (const float*)d_in[0];
  const float* Wih  = (const float*)d_in[34];
  const float* Whh  = (const float*)d_in[35];
  const float* bih  = (const float*)d_in[36];
  const float* bhh  = (const float*)d_in[37];
  const float* attnW= (const float*)d_in[38];
  const float* attnB= (const float*)d_in[39];
  const float* W1   = (const float*)d_in[40];
  const float* b1   = (const float*)d_in[41];
  const float* W2   = (const float*)d_in[42];
  const float* b2   = (const float*)d_in[43];

  char* w = (char*)d_ws;
  size_t o = 0;
  unsigned short* cat    = (unsigned short*)(w+o); o += (size_t)NS*TS*512*2;      // 64 MiB
  unsigned short* eqk    = (unsigned short*)(w+o); o += (size_t)6*NS*TS*128*2;    // 96 MiB
  unsigned short* eeb    = (unsigned short*)(w+o); o += (size_t)3*EE*128*2;       // 24 MiB
  unsigned short* ft     = (unsigned short*)(w+o); o += (size_t)3*NS*TS*128*2;    // 48 MiB
  unsigned short* pooled = (unsigned short*)(w+o); o += (size_t)NS*512*2;         // 4 MiB
  float* sf   = (float*)(w+o); o += (size_t)NS*TS*DF*4;
  float* hmlp = (float*)(w+o); o += (size_t)NS*HD*4;
  unsigned short* whhB = (unsigned short*)(w+o); o += (size_t)512*128*2;
  int* cnt  = (int*)(w+o); o += 3*4096*4;
  int* rs   = (int*)(w+o); o += 3*4097*4;
  int* woff = (int*)(w+o); o += 3*4096*4;
  int* eidx = (int*)(w+o); o += (size_t)3*EE*4;

  P3 srcs = {{ (const int*)d_in[1], (const int*)d_in[12], (const int*)d_in[23] }};

  // D1: prolog
  k_prolog<<<384, 256, 0, stream>>>(x, sf, Whh, whhB, cnt);

  // D2: mega1 = lstm | ee GEMM | count
  {
    M1 p;
    p.sf = sf; p.Wih = Wih; p.bih = bih; p.bhh = bhh;
    p.WhhB = whhB; p.cat = cat; p.eeb = eeb; p.cnt = cnt;
    for (int g=0; g<3; g++){
      int base = 1 + g*11;
      p.ef[g] = (const float*)d_in[base+2];
      p.We[g] = (const float*)d_in[base+7];
      p.be[g] = (const float*)d_in[base+8];
      p.dst[g] = (const int*)d_in[base+1];
    }
    k_mega1<<<1664, 256, 0, stream>>>(p);
  }

  // D3: scan
  k_scan<<<3, 1024, 0, stream>>>(cnt, rs, woff);

  // D4: mega2 = QK GEMM | fill
  {
    M2 p;
    p.cat = cat; p.eqk = eqk; p.woff = woff; p.eidx = eidx;
    for (int g=0; g<3; g++){
      int base = 1 + g*11;
      p.W[2*g]      = (const float*)d_in[base+3]; // Wq
      p.bias[2*g]   = (const float*)d_in[base+4];
      p.W[2*g+1]    = (const float*)d_in[base+5]; // Wk
      p.bias[2*g+1] = (const float*)d_in[base+6];
      p.dst[g] = (const int*)d_in[base+1];
    }
    k_mega2<<<3456, 256, 0, stream>>>(p);
  }

  // D5: edge gather, t-sliced
  k_edge<<<dim3(256,16,3), 256, 0, stream>>>(eqk, eeb, srcs, rs, eidx, ft);

  // D6: Wr GEMMs
  {
    WrP p;
    for (int g=0; g<3; g++){
      int base = 1 + g*11;
      p.A[g]    = ft + (size_t)g*NS*TS*128;
      p.B[g]    = (const float*)d_in[base+9];
      p.bias[g] = (const float*)d_in[base+10];
      p.C[g]    = cat + (size_t)(1+g)*128;
    }
    k_wr<<<dim3(3,512), 256, 0, stream>>>(p);
  }

  // D7: attention + pooling
  k_attn<<<NS, 256, 0, stream>>>(cat, attnW, attnB, pooled);
  // D8: MLP1
  k_mlp<<<32, 256, 0, stream>>>(pooled, W1, b1, hmlp);
  // D9: final
  k_final<<<NS/4, 256, 0, stream>>>(hmlp, W2, b2, sf, (float*)d_out);
}

// Round 7
// 380.363 us; speedup vs baseline: 2.3976x; 1.0938x over previous
//
#include <hip/hip_runtime.h>
#include <cstdint>
#include <cstddef>

#define NS 4096
#define TS 16
#define DF 5
#define HD 128
#define EE 32768
#define EDD 32

typedef _Float16 h16;
typedef __attribute__((ext_vector_type(8))) _Float16 f16x8;
typedef __attribute__((ext_vector_type(2))) __fp16 fp16x2_n;  // builtin's native type
typedef __attribute__((ext_vector_type(4))) float f32x4;

__device__ __forceinline__ float sigmoidf_(float x){ return 1.f/(1.f+__expf(-x)); }
__device__ __forceinline__ float tanhf_(float x){ return 1.f - 2.f/(1.f+__expf(2.f*x)); }
__device__ __forceinline__ float leaky_(float x){ return x >= 0.f ? x : 0.2f*x; }

__device__ __forceinline__ unsigned pkh(float a, float b){
  union { fp16x2_n h; unsigned u; } x;
  x.h = __builtin_amdgcn_cvt_pkrtz(a, b);
  return x.u;
}
__device__ __forceinline__ void unpkh(unsigned u, float& a, float& b){
  union { unsigned u; fp16x2_n h; } x; x.u = u;
  a = (float)x.h.x; b = (float)x.h.y;
}
__device__ __forceinline__ f16x8 ld_h8(const h16* p){
  union { uint4 u; f16x8 v; } x; x.u = *(const uint4*)p; return x.v;
}

// ================= generic MFMA GEMM device function (fp16) =================
// C = act(A[M,K] @ B[128,K]^T + bias), BM=128, BN=128, BK=32, 256 thr.
// AH: A is fp16 (else fp32, converted in staging). CH: C stored fp16.
template<int AH, int CH>
__device__ __forceinline__ void gemm_dev(const void* Av, int lda,
    const float* __restrict__ Bp, int ldb, const float* __restrict__ bp,
    void* Cv, int ldc, int K, int act, size_t m0,
    h16* Asb, h16* Bsb)
{
  int tid = threadIdx.x;
  int wv = tid>>6, lane = tid&63, lm = lane&15, lq = lane>>4;
  f32x4 acc[2][8];
  #pragma unroll
  for (int mt=0;mt<2;mt++)
    #pragma unroll
    for (int nt=0;nt<8;nt++)
      acc[mt][nt] = (f32x4){0.f,0.f,0.f,0.f};

  for (int k0=0; k0<K; k0+=32){
    if (AH){
      const h16* A = (const h16*)Av;
      #pragma unroll
      for (int rep=0;rep<2;rep++){
        int idx = tid + rep*256;
        int row = idx>>2, c8 = idx&3;
        *(uint4*)&Asb[row*40 + c8*8] = *(const uint4*)&A[(m0+row)*(size_t)lda + k0 + c8*8];
      }
    } else {
      const float* A = (const float*)Av;
      #pragma unroll
      for (int rep=0;rep<4;rep++){
        int idx = tid + rep*256;
        int row = idx>>3, c4 = idx&7;
        float4 a = *(const float4*)&A[(m0+row)*(size_t)lda + k0 + c4*4];
        *(uint2*)&Asb[row*40 + c4*4] = make_uint2(pkh(a.x,a.y), pkh(a.z,a.w));
      }
    }
    #pragma unroll
    for (int rep=0;rep<4;rep++){
      int idx = tid + rep*256;
      int row = idx>>3, c4 = idx&7;
      float4 b = *(const float4*)&Bp[(size_t)row*ldb + k0 + c4*4];
      *(uint2*)&Bsb[row*40 + c4*4] = make_uint2(pkh(b.x,b.y), pkh(b.z,b.w));
    }
    __syncthreads();
    f16x8 afr[2], bfr[8];
    #pragma unroll
    for (int mt=0;mt<2;mt++)
      afr[mt] = ld_h8(&Asb[(wv*32 + mt*16 + lm)*40 + lq*8]);
    #pragma unroll
    for (int nt=0;nt<8;nt++)
      bfr[nt] = ld_h8(&Bsb[(nt*16 + lm)*40 + lq*8]);
    #pragma unroll
    for (int mt=0;mt<2;mt++)
      #pragma unroll
      for (int nt=0;nt<8;nt++)
        acc[mt][nt] = __builtin_amdgcn_mfma_f32_16x16x32_f16(afr[mt], bfr[nt], acc[mt][nt], 0,0,0);
    __syncthreads();
  }

  #pragma unroll
  for (int mt=0;mt<2;mt++){
    #pragma unroll
    for (int nt=0;nt<8;nt++){
      int col = nt*16 + lm;
      float bv = bp[col];
      #pragma unroll
      for (int i=0;i<4;i++){
        float o = acc[mt][nt][i] + bv;
        if (act) o = leaky_(o);
        size_t ridx = (m0 + wv*32 + mt*16 + lq*4 + i)*(size_t)ldc + col;
        if (CH) ((h16*)Cv)[ridx] = (h16)o;
        else    ((float*)Cv)[ridx] = o;
      }
    }
  }
}

// ================= LSTM 8 rows/block device function (fp16 MFMA) =================
__device__ void lstm8_dev(int blk, const float* __restrict__ sf,
                          const h16* __restrict__ WhhH,
                          const float* __restrict__ Wih, const float* __restrict__ bih,
                          const float* __restrict__ bhh, h16* __restrict__ cat,
                          char* smem)
{
  float* gates = (float*)smem;                 // 8*516*4 = 16512
  h16* hbuf = (h16*)(smem+16512);              // 8*136*2 = 2176
  float* sfb = (float*)(smem+16512+2176);      // 8*80*4  = 2560
  int tid = threadIdx.x;
  int n0 = blk*8;
  int wv = tid>>6, lane = tid&63, lm = lane&15, lq = lane>>4;

  f16x8 bfr[8][4];
  #pragma unroll
  for (int nt=0;nt<8;nt++){
    int g = wv*128 + nt*16 + lm;
    #pragma unroll
    for (int kt=0;kt<4;kt++)
      bfr[nt][kt] = *(const f16x8*)&WhhH[g*128 + kt*32 + lq*8];
  }

  int j = tid & 127;
  int rb = tid >> 7;
  float wih[4][5]; float bsum[4];
  #pragma unroll
  for (int gi=0; gi<4; gi++){
    int gc = gi*128 + j;
    #pragma unroll
    for (int d=0; d<5; d++) wih[gi][d] = Wih[gc*5+d];
    bsum[gi] = bih[gc] + bhh[gc];
  }
  float cst[4] = {0.f,0.f,0.f,0.f};

  for (int i=tid;i<544;i+=256) ((unsigned*)hbuf)[i] = 0;
  for (int i=tid;i<640;i+=256) sfb[i] = sf[(size_t)n0*80 + i];
  __syncthreads();

  f16x8 zf = {0,0,0,0,0,0,0,0};
  for (int t=0;t<16;t++){
    f16x8 af[4];
    #pragma unroll
    for (int kt=0;kt<4;kt++)
      af[kt] = (lm < 8) ? *(const f16x8*)&hbuf[lm*136 + kt*32 + lq*8] : zf;
    #pragma unroll
    for (int nt=0;nt<8;nt++){
      f32x4 acc = {0.f,0.f,0.f,0.f};
      #pragma unroll
      for (int kt=0;kt<4;kt++)
        acc = __builtin_amdgcn_mfma_f32_16x16x32_f16(af[kt], bfr[nt][kt], acc, 0,0,0);
      if (lq < 2){
        int col = wv*128 + nt*16 + lm;
        #pragma unroll
        for (int i=0;i<4;i++)
          gates[(lq*4+i)*516 + col] = acc[i];
      }
    }
    __syncthreads();
    #pragma unroll
    for (int q=0;q<4;q++){
      int r = rb + 2*q;
      const float* s = &sfb[r*80 + t*5];
      float pre[4];
      #pragma unroll
      for (int gi=0;gi<4;gi++){
        float a = bsum[gi];
        #pragma unroll
        for (int d=0;d<5;d++) a = fmaf(s[d], wih[gi][d], a);
        pre[gi] = a + gates[r*516 + gi*128 + j];
      }
      float iv = sigmoidf_(pre[0]);
      float fv = sigmoidf_(pre[1]);
      float gv = tanhf_(pre[2]);
      float ov = sigmoidf_(pre[3]);
      float c = fv*cst[q] + iv*gv;
      cst[q] = c;
      float h = ov*tanhf_(c);
      h16 hh = (h16)h;
      hbuf[r*136 + j] = hh;
      cat[(size_t)((n0+r)*16 + t)*512 + j] = hh;
    }
    __syncthreads();
  }
}

// ================= prolog: sf | cvt Whh | zero cnt =================
__global__ __launch_bounds__(256)
void k_prolog(const float* __restrict__ x, float* __restrict__ sf,
              const float* __restrict__ Whh, h16* __restrict__ whhH,
              int* __restrict__ cnt)
{
  int b = blockIdx.x, tid = threadIdx.x;
  if (b < 80){
    int id = b*256 + tid;
    if (id < NS*DF){
      int n = id / DF, d = id % DF;
      const float* xp = x + (size_t)n*TS*DF + d;
      float s = 0.f;
      #pragma unroll
      for (int t=0;t<TS;t++) s += xp[t*DF];
      float inv = (float)TS / s;
      float* sp = sf + (size_t)n*TS*DF + d;
      #pragma unroll
      for (int t=0;t<TS;t++) sp[t*DF] = xp[t*DF]*inv;
    }
  } else if (b < 336){
    int i = (b-80)*256 + tid;
    whhH[i] = (h16)Whh[i];
  } else {
    int i = (b-336)*256 + tid;
    cnt[i] = 0;
  }
}

// ================= mega1: lstm (512) | ee GEMM (768) | count (384) =================
struct M1 {
  const float *sf, *Wih, *bih, *bhh;
  const h16* WhhH;
  h16* cat;
  const float *ef[3]; const float *We[3]; const float *be[3];
  h16* eeb;
  const int* dst[3];
  int* cnt;
};
__global__ __launch_bounds__(256,2)
void k_mega1(M1 p)
{
  __shared__ __align__(16) char smem[21504];
  int b = blockIdx.x;
  if (b < 512){
    lstm8_dev(b, p.sf, p.WhhH, p.Wih, p.bih, p.bhh, p.cat, smem);
  } else if (b < 1280){
    int idx = b - 512;
    int proj = idx % 3, mt = idx / 3;
    h16* Asb = (h16*)smem;
    h16* Bsb = Asb + 128*40;
    gemm_dev<0,1>(p.ef[proj], 32, p.We[proj], 32, p.be[proj],
                  p.eeb + (size_t)proj*EE*128, 128, 32, 0, (size_t)mt*128, Asb, Bsb);
  } else {
    int idx = b - 1280;
    int g = idx >> 7, blk = idx & 127;
    int e = blk*256 + threadIdx.x;
    atomicAdd(&p.cnt[g*4096 + p.dst[g][e]], 1);
  }
}

// ================= scan =================
__global__ __launch_bounds__(1024)
void k_scan(const int* __restrict__ cnt_, int* __restrict__ rs_, int* __restrict__ woff_){
  __shared__ int buf[1024];
  int g = blockIdx.x;
  const int* cnt = cnt_ + g*4096;
  int* rs = rs_ + g*4097;
  int* woff = woff_ + g*4096;
  int tid = threadIdx.x;
  int b = tid*4;
  int v0=cnt[b],v1=cnt[b+1],v2=cnt[b+2],v3=cnt[b+3];
  int s = v0+v1+v2+v3;
  buf[tid]=s;
  __syncthreads();
  for (int off=1; off<1024; off<<=1){
    int t = (tid>=off) ? buf[tid-off] : 0;
    __syncthreads();
    buf[tid] += t;
    __syncthreads();
  }
  int excl = buf[tid] - s;
  rs[b+0]=excl; woff[b+0]=excl; excl+=v0;
  rs[b+1]=excl; woff[b+1]=excl; excl+=v1;
  rs[b+2]=excl; woff[b+2]=excl; excl+=v2;
  rs[b+3]=excl; woff[b+3]=excl;
  if (tid==1023) rs[4096]=excl+v3;
}

// ================= mega2: QK GEMM (3072) | fill (384) =================
struct M2 {
  const h16* cat;
  const float* W[6]; const float* bias[6];
  h16* eqk;
  const int* dst[3];
  int* woff; int* eidx;
};
__global__ __launch_bounds__(256)
void k_mega2(M2 p)
{
  __shared__ __align__(16) h16 Asb[128*40];
  __shared__ __align__(16) h16 Bsb[128*40];
  int b = blockIdx.x;
  if (b < 3072){
    int proj = b % 6, mt = b / 6;
    gemm_dev<1,1>(p.cat, 512, p.W[proj], 128, p.bias[proj],
                  p.eqk + (size_t)proj*NS*TS*128, 128, 128, 0, (size_t)mt*128, Asb, Bsb);
  } else {
    int idx = b - 3072;
    int g = idx >> 7, blk = idx & 127;
    int e = blk*256 + threadIdx.x;
    int pos = atomicAdd(&p.woff[g*4096 + p.dst[g][e]], 1);
    p.eidx[g*EE + pos] = e;
  }
}

// ================= k_edge: node-per-block, packed fp16 math, grid (NS,3) =================
struct P3 { const int* p[3]; };
__global__ __launch_bounds__(256)
void k_edge(const h16* __restrict__ eqk, const h16* __restrict__ eeb,
            P3 src, const int* __restrict__ rs_, const int* __restrict__ eidx_,
            h16* __restrict__ ft_)
{
  int n = blockIdx.x;
  int g = blockIdx.y;
  const h16* eqb = eqk + (size_t)(2*g)  *NS*TS*128;
  const h16* ekb = eqk + (size_t)(2*g+1)*NS*TS*128;
  const h16* eeg = eeb + (size_t)g*EE*128;
  h16* ft = ft_ + (size_t)g*NS*TS*128;
  const int* srcp = src.p[g];
  const int* rs = rs_ + g*4097;
  const int* eidx = eidx_ + g*EE;
  int tid = threadIdx.x;
  int t = tid>>4, hb = (tid&15)*8;
  size_t own = ((size_t)(n*16+t))*128 + hb;
  f16x8 eqv = ld_h8(&eqb[own]);
  const f16x8 c02 = {(h16)0.2f,(h16)0.2f,(h16)0.2f,(h16)0.2f,
                     (h16)0.2f,(h16)0.2f,(h16)0.2f,(h16)0.2f};
  float acc[8];
  #pragma unroll
  for (int j=0;j<8;j++) acc[j]=0.f;
  int i0 = rs[n], i1 = rs[n+1];
  for (int i=i0;i<i1;i++){
    int e = eidx[i];
    int s = srcp[e];
    f16x8 kv = ld_h8(&ekb[((size_t)(s*16+t))*128 + hb]);
    f16x8 ev = ld_h8(&eeg[(size_t)e*128 + hb]);
    f16x8 x = eqv + kv + ev;                        // v_pk_add_f16
    f16x8 lk = __builtin_elementwise_max(x, x*c02); // packed leaky
    #pragma unroll
    for (int j=0;j<8;j++) acc[j] += (float)lk[j];   // fp32 accumulate
  }
  uint4 o;
  o.x = pkh(acc[0],acc[1]); o.y = pkh(acc[2],acc[3]);
  o.z = pkh(acc[4],acc[5]); o.w = pkh(acc[6],acc[7]);
  *(uint4*)&ft[own] = o;
}

// ================= Wr GEMM: grid (3,512) =================
struct WrP {
  const h16* A[3];
  const float* B[3]; const float* bias[3];
  h16* C[3];
};
__global__ __launch_bounds__(256)
void k_wr(WrP p)
{
  __shared__ __align__(16) h16 Asb[128*40];
  __shared__ __align__(16) h16 Bsb[128*40];
  int proj = blockIdx.x;
  size_t m0 = (size_t)blockIdx.y * 128;
  gemm_dev<1,1>(p.A[proj], 128, p.B[proj], 128, p.bias[proj],
                p.C[proj], 512, 128, 0, m0, Asb, Bsb);
}

// ================= attention + pooling (fp16 cat/pooled) =================
__global__ __launch_bounds__(256)
void k_attn(const h16* __restrict__ cat, const float* __restrict__ attnW,
            const float* __restrict__ attnB, h16* __restrict__ pooled)
{
  __shared__ h16 ct[16*512];
  __shared__ float sred[4][16];
  int n = blockIdx.x, tid = threadIdx.x;
  {
    const uint4* srcp = (const uint4*)(cat + (size_t)n*8192);
    uint4* dstp = (uint4*)ct;
    for (int i=tid;i<1024;i+=256) dstp[i] = srcp[i];
  }
  __syncthreads();
  int c0 = tid*2;
  float w0 = attnW[c0], w1 = attnW[c0+1];
  const unsigned* ctu = (const unsigned*)ct;
  float loc[16];
  #pragma unroll
  for (int t=0;t<16;t++){
    float a,b; unpkh(ctu[t*256 + tid], a, b);
    loc[t] = a*w0 + b*w1;
  }
  #pragma unroll
  for (int t=0;t<16;t++){
    float v = loc[t];
    for (int off=1; off<64; off<<=1) v += __shfl_xor(v, off, 64);
    loc[t]=v;
  }
  int wave = tid >> 6, lane = tid & 63;
  if (lane==0){
    #pragma unroll
    for (int t=0;t<16;t++) sred[wave][t]=loc[t];
  }
  __syncthreads();
  float s[16]; float m=-1e30f;
  float ab = attnB[0];
  #pragma unroll
  for (int t=0;t<16;t++){ s[t] = sred[0][t]+sred[1][t]+sred[2][t]+sred[3][t] + ab; m = fmaxf(m, s[t]); }
  float sum=0.f;
  #pragma unroll
  for (int t=0;t<16;t++){ s[t] = __expf(s[t]-m); sum += s[t]; }
  float inv = 1.f/sum;
  float p0=0.f,p1=0.f;
  #pragma unroll
  for (int t=0;t<16;t++){
    float a = s[t]*inv;
    float x,y; unpkh(ctu[t*256 + tid], x, y);
    p0 = fmaf(x, a, p0); p1 = fmaf(y, a, p1);
  }
  ((unsigned*)pooled)[(size_t)n*256 + tid] = pkh(p0,p1);
}

// ================= MLP1 GEMM: grid 32 =================
__global__ __launch_bounds__(256)
void k_mlp(const h16* __restrict__ pooled, const float* __restrict__ W1,
           const float* __restrict__ b1, float* __restrict__ hmlp)
{
  __shared__ __align__(16) h16 Asb[128*40];
  __shared__ __align__(16) h16 Bsb[128*40];
  gemm_dev<1,0>(pooled, 512, W1, 512, b1, hmlp, 128, 512, 1,
                (size_t)blockIdx.x*128, Asb, Bsb);
}

// ================= final =================
__global__ __launch_bounds__(256)
void k_final(const float* __restrict__ hmlp, const float* __restrict__ W2,
             const float* __restrict__ b2, const float* __restrict__ sf,
             float* __restrict__ out)
{
  int tid = threadIdx.x;
  int n = blockIdx.x*4 + (tid>>6);
  int lane = tid & 63;
  const float* hp = hmlp + (size_t)n*128;
  float v = hp[lane]*W2[lane] + hp[64+lane]*W2[64+lane];
  for (int off=1; off<64; off<<=1) v += __shfl_xor(v, off, 64);
  if (lane==0){
    float o = v + b2[0];
    o = leaky_(o);
    out[n] = o / sf[(size_t)n*80 + 75] - 1.f;
  }
}

extern "C" void kernel_launch(void* const* d_in, const int* in_sizes, int n_in,
                              void* d_out, int out_size, void* d_ws, size_t ws_size,
                              hipStream_t stream)
{
  const float* x    = (const float*)d_in[0];
  const float* Wih  = (const float*)d_in[34];
  const float* Whh  = (const float*)d_in[35];
  const float* bih  = (const float*)d_in[36];
  const float* bhh  = (const float*)d_in[37];
  const float* attnW= (const float*)d_in[38];
  const float* attnB= (const float*)d_in[39];
  const float* W1   = (const float*)d_in[40];
  const float* b1   = (const float*)d_in[41];
  const float* W2   = (const float*)d_in[42];
  const float* b2   = (const float*)d_in[43];

  char* w = (char*)d_ws;
  size_t o = 0;
  h16* cat    = (h16*)(w+o); o += (size_t)NS*TS*512*2;      // 64 MiB
  h16* eqk    = (h16*)(w+o); o += (size_t)6*NS*TS*128*2;    // 96 MiB
  h16* eeb    = (h16*)(w+o); o += (size_t)3*EE*128*2;       // 24 MiB
  h16* ft     = (h16*)(w+o); o += (size_t)3*NS*TS*128*2;    // 48 MiB
  h16* pooled = (h16*)(w+o); o += (size_t)NS*512*2;         // 4 MiB
  float* sf   = (float*)(w+o); o += (size_t)NS*TS*DF*4;
  float* hmlp = (float*)(w+o); o += (size_t)NS*HD*4;
  h16* whhH = (h16*)(w+o); o += (size_t)512*128*2;
  int* cnt  = (int*)(w+o); o += 3*4096*4;
  int* rs   = (int*)(w+o); o += 3*4097*4;
  int* woff = (int*)(w+o); o += 3*4096*4;
  int* eidx = (int*)(w+o); o += (size_t)3*EE*4;

  P3 srcs = {{ (const int*)d_in[1], (const int*)d_in[12], (const int*)d_in[23] }};

  // D1: prolog
  k_prolog<<<384, 256, 0, stream>>>(x, sf, Whh, whhH, cnt);

  // D2: mega1 = lstm | ee GEMM | count
  {
    M1 p;
    p.sf = sf; p.Wih = Wih; p.bih = bih; p.bhh = bhh;
    p.WhhH = whhH; p.cat = cat; p.eeb = eeb; p.cnt = cnt;
    for (int g=0; g<3; g++){
      int base = 1 + g*11;
      p.ef[g] = (const float*)d_in[base+2];
      p.We[g] = (const float*)d_in[base+7];
      p.be[g] = (const float*)d_in[base+8];
      p.dst[g] = (const int*)d_in[base+1];
    }
    k_mega1<<<1664, 256, 0, stream>>>(p);
  }

  // D3: scan
  k_scan<<<3, 1024, 0, stream>>>(cnt, rs, woff);

  // D4: mega2 = QK GEMM | fill
  {
    M2 p;
    p.cat = cat; p.eqk = eqk; p.woff = woff; p.eidx = eidx;
    for (int g=0; g<3; g++){
      int base = 1 + g*11;
      p.W[2*g]      = (const float*)d_in[base+3]; // Wq
      p.bias[2*g]   = (const float*)d_in[base+4];
      p.W[2*g+1]    = (const float*)d_in[base+5]; // Wk
      p.bias[2*g+1] = (const float*)d_in[base+6];
      p.dst[g] = (const int*)d_in[base+1];
    }
    k_mega2<<<3456, 256, 0, stream>>>(p);
  }

  // D5: edge gather (node-per-block, uniform edge lists)
  k_edge<<<dim3(NS,3), 256, 0, stream>>>(eqk, eeb, srcs, rs, eidx, ft);

  // D6: Wr GEMMs
  {
    WrP p;
    for (int g=0; g<3; g++){
      int base = 1 + g*11;
      p.A[g]    = ft + (size_t)g*NS*TS*128;
      p.B[g]    = (const float*)d_in[base+9];
      p.bias[g] = (const float*)d_in[base+10];
      p.C[g]    = cat + (size_t)(1+g)*128;
    }
    k_wr<<<dim3(3,512), 256, 0, stream>>>(p);
  }

  // D7: attention + pooling
  k_attn<<<NS, 256, 0, stream>>>(cat, attnW, attnB, pooled);
  // D8: MLP1
  k_mlp<<<32, 256, 0, stream>>>(pooled, W1, b1, hmlp);
  // D9: final
  k_final<<<NS/4, 256, 0, stream>>>(hmlp, W2, b2, sf, (float*)d_out);
}